// Round 1
// baseline (1429.581 us; speedup 1.0000x reference)
//
#include <hip/hip_runtime.h>
#include <hip/hip_bf16.h>

#define LRELU(v) ((v) > 0.0f ? (v) : 0.2f * (v))
#define NEGBIG (-3.4e38f)

// ---------------- CSR build ----------------
__global__ void k_hist(const int* __restrict__ ei, int* __restrict__ deg, int E, int N) {
    int e = blockIdx.x * blockDim.x + threadIdx.x;
    if (e >= E + N) return;
    int d = (e < E) ? ei[E + e] : (e - E);
    atomicAdd(&deg[d], 1);
}

__global__ void k_scan(const int* __restrict__ deg, int* __restrict__ rowp,
                       int* __restrict__ cursor, int N) {
    __shared__ int wsum[16];
    int t = threadIdx.x;            // 1024 threads
    int lane = t & 63;
    int w = t >> 6;
    int carry = 0;
    int nch = (N + 1023) >> 10;
    for (int c = 0; c < nch; ++c) {
        int idx = (c << 10) + t;
        int v = (idx < N) ? deg[idx] : 0;
        int sv = v;
        #pragma unroll
        for (int o = 1; o < 64; o <<= 1) {
            int u = __shfl_up(sv, o, 64);
            if (lane >= o) sv += u;
        }
        if (lane == 63) wsum[w] = sv;
        __syncthreads();
        if (t < 16) {
            int ws2 = wsum[t];
            #pragma unroll
            for (int o = 1; o < 16; o <<= 1) {
                int u = __shfl_up(ws2, o, 16);
                if (t >= o) ws2 += u;
            }
            wsum[t] = ws2;
        }
        __syncthreads();
        int woff = (w > 0) ? wsum[w - 1] : 0;
        int excl = sv - v + woff + carry;
        if (idx < N) { rowp[idx] = excl; cursor[idx] = excl; }
        carry += wsum[15];
        __syncthreads();
    }
    if (t == 0) rowp[N] = carry;
}

__global__ void k_scatter(const int* __restrict__ ei, int* __restrict__ cursor,
                          int* __restrict__ col, int E, int N) {
    int e = blockIdx.x * blockDim.x + threadIdx.x;
    if (e >= E + N) return;
    int sN, dN;
    if (e < E) { sN = ei[e]; dN = ei[E + e]; } else { sN = dN = e - E; }
    int pos = atomicAdd(&cursor[dN], 1);
    col[pos] = sN;
}

// ---------------- layer-1 constants: ds[h] = <W1[h,:], a_src1[h,:]>, dd[h] likewise ----------------
__global__ void k_pre(const float* __restrict__ W1, const float* __restrict__ a1s,
                      const float* __restrict__ a1d, float* __restrict__ dots) {
    int t = threadIdx.x;            // 128 threads
    float w = W1[t];
    float ps = w * a1s[t];
    float pd = w * a1d[t];
    #pragma unroll
    for (int o = 16; o; o >>= 1) {
        ps += __shfl_xor(ps, o, 32);
        pd += __shfl_xor(pd, o, 32);
    }
    if ((t & 31) == 0) {
        dots[t >> 5] = ps;
        dots[4 + (t >> 5)] = pd;
    }
}

// ---------------- layer 1: per-node 4-head scalar attention; S[n,h] = sum alpha*x_src ----------------
__global__ void k_layer1(const float* __restrict__ x, const int* __restrict__ rowp,
                         const int* __restrict__ col, const float* __restrict__ dots,
                         float* __restrict__ S, int N) {
    int gid = blockIdx.x * blockDim.x + threadIdx.x;
    int n = gid >> 4;               // 16 lanes per node
    int lane = threadIdx.x & 15;
    if (n >= N) return;
    int s = rowp[n];
    int deg = rowp[n + 1] - s;
    float xd = x[n];
    float ds0 = dots[0], ds1 = dots[1], ds2 = dots[2], ds3 = dots[3];
    float t0 = xd * dots[4], t1 = xd * dots[5], t2 = xd * dots[6], t3 = xd * dots[7];
    float m0 = NEGBIG, m1 = NEGBIG, m2 = NEGBIG, m3 = NEGBIG;
    for (int i = lane; i < deg; i += 16) {
        float xs = x[col[s + i]];
        float e0 = LRELU(fmaf(xs, ds0, t0)); m0 = fmaxf(m0, e0);
        float e1 = LRELU(fmaf(xs, ds1, t1)); m1 = fmaxf(m1, e1);
        float e2 = LRELU(fmaf(xs, ds2, t2)); m2 = fmaxf(m2, e2);
        float e3 = LRELU(fmaf(xs, ds3, t3)); m3 = fmaxf(m3, e3);
    }
    #pragma unroll
    for (int o = 8; o; o >>= 1) {
        m0 = fmaxf(m0, __shfl_xor(m0, o, 16));
        m1 = fmaxf(m1, __shfl_xor(m1, o, 16));
        m2 = fmaxf(m2, __shfl_xor(m2, o, 16));
        m3 = fmaxf(m3, __shfl_xor(m3, o, 16));
    }
    float p0 = 0.f, p1 = 0.f, p2 = 0.f, p3 = 0.f;
    float q0 = 0.f, q1 = 0.f, q2 = 0.f, q3 = 0.f;
    for (int i = lane; i < deg; i += 16) {
        float xs = x[col[s + i]];
        float e0 = __expf(LRELU(fmaf(xs, ds0, t0)) - m0); p0 += e0; q0 = fmaf(e0, xs, q0);
        float e1 = __expf(LRELU(fmaf(xs, ds1, t1)) - m1); p1 += e1; q1 = fmaf(e1, xs, q1);
        float e2 = __expf(LRELU(fmaf(xs, ds2, t2)) - m2); p2 += e2; q2 = fmaf(e2, xs, q2);
        float e3 = __expf(LRELU(fmaf(xs, ds3, t3)) - m3); p3 += e3; q3 = fmaf(e3, xs, q3);
    }
    #pragma unroll
    for (int o = 8; o; o >>= 1) {
        p0 += __shfl_xor(p0, o, 16); p1 += __shfl_xor(p1, o, 16);
        p2 += __shfl_xor(p2, o, 16); p3 += __shfl_xor(p3, o, 16);
        q0 += __shfl_xor(q0, o, 16); q1 += __shfl_xor(q1, o, 16);
        q2 += __shfl_xor(q2, o, 16); q3 += __shfl_xor(q3, o, 16);
    }
    if (lane == 0) {
        float4 r;
        r.x = q0 / (p0 + 1e-16f);
        r.y = q1 / (p1 + 1e-16f);
        r.z = q2 / (p2 + 1e-16f);
        r.w = q3 / (p3 + 1e-16f);
        *(float4*)(S + n * 4) = r;
    }
}

// ---------------- layer 2 node transform: h2 = relu(S*W1+b1) @ W2; e_src2/e_dst2 ----------------
__global__ void k_h2(const float* __restrict__ S, const float* __restrict__ W1,
                     const float* __restrict__ b1, const float* __restrict__ W2,
                     const float* __restrict__ a2s, const float* __restrict__ a2d,
                     float* __restrict__ h2, float* __restrict__ es2,
                     float* __restrict__ ed2, int N) {
    __shared__ float sW2[4096];
    __shared__ float sW1[128];
    __shared__ float sb1[128];
    for (int i = threadIdx.x; i < 4096; i += blockDim.x) sW2[i] = W2[i];
    if (threadIdx.x < 128) {
        sW1[threadIdx.x] = W1[threadIdx.x];
        sb1[threadIdx.x] = b1[threadIdx.x];
    }
    __syncthreads();
    int n = blockIdx.x * blockDim.x + threadIdx.x;
    if (n >= N) return;
    float sv0 = S[n * 4 + 0], sv1 = S[n * 4 + 1], sv2 = S[n * 4 + 2], sv3 = S[n * 4 + 3];
    float acc[32];
    #pragma unroll
    for (int c = 0; c < 32; ++c) acc[c] = 0.f;
    #pragma unroll
    for (int h = 0; h < 4; ++h) {
        float sh = (h == 0) ? sv0 : (h == 1) ? sv1 : (h == 2) ? sv2 : sv3;
        for (int cc = 0; cc < 32; ++cc) {
            int hc = h * 32 + cc;
            float x1 = fmaf(sh, sW1[hc], sb1[hc]);
            x1 = x1 > 0.f ? x1 : 0.f;
            const float* w2row = &sW2[hc * 32];
            #pragma unroll
            for (int c = 0; c < 32; ++c) acc[c] = fmaf(x1, w2row[c], acc[c]);
        }
    }
    float es = 0.f, edv = 0.f;
    #pragma unroll
    for (int c = 0; c < 32; ++c) {
        es = fmaf(acc[c], a2s[c], es);
        edv = fmaf(acc[c], a2d[c], edv);
    }
    float4* h2v = (float4*)(h2 + (size_t)n * 32);
    #pragma unroll
    for (int q = 0; q < 8; ++q)
        h2v[q] = make_float4(acc[q * 4], acc[q * 4 + 1], acc[q * 4 + 2], acc[q * 4 + 3]);
    es2[n] = es;
    ed2[n] = edv;
}

// ---------------- layer 2 aggregation + fused mean-pool accumulate ----------------
__global__ void k_agg(const float* __restrict__ h2, const float* __restrict__ es2,
                      const float* __restrict__ ed2, const int* __restrict__ rowp,
                      const int* __restrict__ col, const float* __restrict__ b2,
                      const int* __restrict__ batch, float* __restrict__ pooled,
                      float* __restrict__ cnt, int N) {
    int gid = blockIdx.x * blockDim.x + threadIdx.x;
    int n = gid >> 5;               // 32 lanes per node: lane = channel
    int lane = threadIdx.x & 31;
    if (n >= N) return;
    int s = rowp[n];
    int deg = rowp[n + 1] - s;
    float ed = ed2[n];
    float m = NEGBIG;
    for (int i = lane; i < deg; i += 32) {
        float e = LRELU(es2[col[s + i]] + ed);
        m = fmaxf(m, e);
    }
    #pragma unroll
    for (int o = 16; o; o >>= 1) m = fmaxf(m, __shfl_xor(m, o, 32));
    float acc = 0.f, sump = 0.f;
    for (int j = 0; j < deg; ++j) {
        int sidx = col[s + j];
        float p = __expf(LRELU(es2[sidx] + ed) - m);
        sump += p;
        acc = fmaf(p, h2[(size_t)sidx * 32 + lane], acc);
    }
    float o2 = acc / (sump + 1e-16f);
    float x2 = o2 + b2[lane];
    x2 = x2 > 0.f ? x2 : 0.f;
    int g = batch[n];
    atomicAdd(&pooled[g * 32 + lane], x2);
    if (lane == 0) atomicAdd(&cnt[g], 1.0f);
}

// ---------------- final: mean, linear, sigmoid ----------------
__global__ void k_final(const float* __restrict__ pooled, const float* __restrict__ cnt,
                        const float* __restrict__ lin_w, const float* __restrict__ lin_b,
                        float* __restrict__ out, int G) {
    int g = blockIdx.x * blockDim.x + threadIdx.x;
    if (g >= G) return;
    float c = fmaxf(cnt[g], 1.0f);
    float acc = 0.f;
    for (int i = 0; i < 32; ++i) acc = fmaf(pooled[g * 32 + i] / c, lin_w[i], acc);
    acc += lin_b[0];
    out[g] = 1.0f / (1.0f + __expf(-acc));
}

extern "C" void kernel_launch(void* const* d_in, const int* in_sizes, int n_in,
                              void* d_out, int out_size, void* d_ws, size_t ws_size,
                              hipStream_t stream) {
    const float* x     = (const float*)d_in[0];
    const int*   ei    = (const int*)d_in[1];
    const int*   batch = (const int*)d_in[2];
    const float* W1    = (const float*)d_in[4];
    const float* a1s   = (const float*)d_in[5];
    const float* a1d   = (const float*)d_in[6];
    const float* b1    = (const float*)d_in[7];
    const float* W2    = (const float*)d_in[8];
    const float* a2s   = (const float*)d_in[9];
    const float* a2d   = (const float*)d_in[10];
    const float* b2    = (const float*)d_in[11];
    const float* lin_w = (const float*)d_in[12];
    const float* lin_b = (const float*)d_in[13];
    float* out = (float*)d_out;

    int N = in_sizes[0];
    int E = in_sizes[1] / 2;
    int ET = E + N;
    int G = out_size;

    char* ws = (char*)d_ws;
    size_t off = 0;
    auto alloc = [&](size_t bytes) -> char* {
        char* p = ws + off;
        off = (off + bytes + 255) & ~(size_t)255;
        return p;
    };
    int*   deg    = (int*)alloc((size_t)N * 4);
    int*   rowp   = (int*)alloc((size_t)(N + 1) * 4);
    int*   cursor = (int*)alloc((size_t)N * 4);
    int*   col    = (int*)alloc((size_t)ET * 4);
    float* S      = (float*)alloc((size_t)N * 16);
    float* h2     = (float*)alloc((size_t)N * 128);
    float* es2    = (float*)alloc((size_t)N * 4);
    float* ed2    = (float*)alloc((size_t)N * 4);
    float* dots   = (float*)alloc(32);
    float* pooled = (float*)alloc((size_t)G * 128);
    float* cnt    = (float*)alloc((size_t)G * 4);

    hipMemsetAsync(deg, 0, (size_t)N * 4, stream);
    hipMemsetAsync(pooled, 0, (size_t)G * 128, stream);
    hipMemsetAsync(cnt, 0, (size_t)G * 4, stream);

    k_hist<<<(ET + 255) / 256, 256, 0, stream>>>(ei, deg, E, N);
    k_scan<<<1, 1024, 0, stream>>>(deg, rowp, cursor, N);
    k_scatter<<<(ET + 255) / 256, 256, 0, stream>>>(ei, cursor, col, E, N);
    k_pre<<<1, 128, 0, stream>>>(W1, a1s, a1d, dots);
    k_layer1<<<(N + 15) / 16, 256, 0, stream>>>(x, rowp, col, dots, S, N);
    k_h2<<<(N + 255) / 256, 256, 0, stream>>>(S, W1, b1, W2, a2s, a2d, h2, es2, ed2, N);
    k_agg<<<(N + 7) / 8, 256, 0, stream>>>(h2, es2, ed2, rowp, col, b2, batch, pooled, cnt, N);
    k_final<<<1, 64, 0, stream>>>(pooled, cnt, lin_w, lin_b, out, G);
}

// Round 2
// 1334.458 us; speedup vs baseline: 1.0713x; 1.0713x over previous
//
#include <hip/hip_runtime.h>
#include <hip/hip_bf16.h>

#define LRELU(v) ((v) > 0.0f ? (v) : 0.2f * (v))
#define NEGBIG (-3.4e38f)

// ---------------- CSR build ----------------
__global__ void k_hist(const int* __restrict__ ei, int* __restrict__ deg, int E, int N) {
    int e = blockIdx.x * blockDim.x + threadIdx.x;
    if (e >= E + N) return;
    int d = (e < E) ? ei[E + e] : (e - E);
    atomicAdd(&deg[d], 1);
}

__global__ void k_scan(const int* __restrict__ deg, int* __restrict__ rowp,
                       int* __restrict__ cursor, int N) {
    __shared__ int wsum[16];
    int t = threadIdx.x;            // 1024 threads
    int lane = t & 63;
    int w = t >> 6;
    int carry = 0;
    int nch = (N + 1023) >> 10;
    for (int c = 0; c < nch; ++c) {
        int idx = (c << 10) + t;
        int v = (idx < N) ? deg[idx] : 0;
        int sv = v;
        #pragma unroll
        for (int o = 1; o < 64; o <<= 1) {
            int u = __shfl_up(sv, o, 64);
            if (lane >= o) sv += u;
        }
        if (lane == 63) wsum[w] = sv;
        __syncthreads();
        if (t < 16) {
            int ws2 = wsum[t];
            #pragma unroll
            for (int o = 1; o < 16; o <<= 1) {
                int u = __shfl_up(ws2, o, 16);
                if (t >= o) ws2 += u;
            }
            wsum[t] = ws2;
        }
        __syncthreads();
        int woff = (w > 0) ? wsum[w - 1] : 0;
        int excl = sv - v + woff + carry;
        if (idx < N) { rowp[idx] = excl; cursor[idx] = excl; }
        carry += wsum[15];
        __syncthreads();
    }
    if (t == 0) rowp[N] = carry;
}

__global__ void k_scatter(const int* __restrict__ ei, int* __restrict__ cursor,
                          int* __restrict__ col, int E, int N) {
    int e = blockIdx.x * blockDim.x + threadIdx.x;
    if (e >= E + N) return;
    int sN, dN;
    if (e < E) { sN = ei[e]; dN = ei[E + e]; } else { sN = dN = e - E; }
    int pos = atomicAdd(&cursor[dN], 1);
    col[pos] = sN;
}

// ---------------- layer-1 constants ----------------
__global__ void k_pre(const float* __restrict__ W1, const float* __restrict__ a1s,
                      const float* __restrict__ a1d, float* __restrict__ dots) {
    int t = threadIdx.x;            // 128 threads
    float w = W1[t];
    float ps = w * a1s[t];
    float pd = w * a1d[t];
    #pragma unroll
    for (int o = 16; o; o >>= 1) {
        ps += __shfl_xor(ps, o, 32);
        pd += __shfl_xor(pd, o, 32);
    }
    if ((t & 31) == 0) {
        dots[t >> 5] = ps;
        dots[4 + (t >> 5)] = pd;
    }
}

// ---------------- layer 1 ----------------
__global__ void k_layer1(const float* __restrict__ x, const int* __restrict__ rowp,
                         const int* __restrict__ col, const float* __restrict__ dots,
                         float* __restrict__ S, int N) {
    int gid = blockIdx.x * blockDim.x + threadIdx.x;
    int n = gid >> 4;               // 16 lanes per node
    int lane = threadIdx.x & 15;
    if (n >= N) return;
    int s = rowp[n];
    int deg = rowp[n + 1] - s;
    float xd = x[n];
    float ds0 = dots[0], ds1 = dots[1], ds2 = dots[2], ds3 = dots[3];
    float t0 = xd * dots[4], t1 = xd * dots[5], t2 = xd * dots[6], t3 = xd * dots[7];
    float m0 = NEGBIG, m1 = NEGBIG, m2 = NEGBIG, m3 = NEGBIG;
    for (int i = lane; i < deg; i += 16) {
        float xs = x[col[s + i]];
        float e0 = LRELU(fmaf(xs, ds0, t0)); m0 = fmaxf(m0, e0);
        float e1 = LRELU(fmaf(xs, ds1, t1)); m1 = fmaxf(m1, e1);
        float e2 = LRELU(fmaf(xs, ds2, t2)); m2 = fmaxf(m2, e2);
        float e3 = LRELU(fmaf(xs, ds3, t3)); m3 = fmaxf(m3, e3);
    }
    #pragma unroll
    for (int o = 8; o; o >>= 1) {
        m0 = fmaxf(m0, __shfl_xor(m0, o, 16));
        m1 = fmaxf(m1, __shfl_xor(m1, o, 16));
        m2 = fmaxf(m2, __shfl_xor(m2, o, 16));
        m3 = fmaxf(m3, __shfl_xor(m3, o, 16));
    }
    float p0 = 0.f, p1 = 0.f, p2 = 0.f, p3 = 0.f;
    float q0 = 0.f, q1 = 0.f, q2 = 0.f, q3 = 0.f;
    for (int i = lane; i < deg; i += 16) {
        float xs = x[col[s + i]];
        float e0 = __expf(LRELU(fmaf(xs, ds0, t0)) - m0); p0 += e0; q0 = fmaf(e0, xs, q0);
        float e1 = __expf(LRELU(fmaf(xs, ds1, t1)) - m1); p1 += e1; q1 = fmaf(e1, xs, q1);
        float e2 = __expf(LRELU(fmaf(xs, ds2, t2)) - m2); p2 += e2; q2 = fmaf(e2, xs, q2);
        float e3 = __expf(LRELU(fmaf(xs, ds3, t3)) - m3); p3 += e3; q3 = fmaf(e3, xs, q3);
    }
    #pragma unroll
    for (int o = 8; o; o >>= 1) {
        p0 += __shfl_xor(p0, o, 16); p1 += __shfl_xor(p1, o, 16);
        p2 += __shfl_xor(p2, o, 16); p3 += __shfl_xor(p3, o, 16);
        q0 += __shfl_xor(q0, o, 16); q1 += __shfl_xor(q1, o, 16);
        q2 += __shfl_xor(q2, o, 16); q3 += __shfl_xor(q3, o, 16);
    }
    if (lane == 0) {
        float4 r;
        r.x = q0 / (p0 + 1e-16f);
        r.y = q1 / (p1 + 1e-16f);
        r.z = q2 / (p2 + 1e-16f);
        r.w = q3 / (p3 + 1e-16f);
        *(float4*)(S + n * 4) = r;
    }
}

// ---------------- layer 2 node transform ----------------
__global__ void k_h2(const float* __restrict__ S, const float* __restrict__ W1,
                     const float* __restrict__ b1, const float* __restrict__ W2,
                     const float* __restrict__ a2s, const float* __restrict__ a2d,
                     float* __restrict__ h2, float* __restrict__ es2,
                     float* __restrict__ ed2, int N) {
    __shared__ float sW2[4096];
    __shared__ float sW1[128];
    __shared__ float sb1[128];
    for (int i = threadIdx.x; i < 4096; i += blockDim.x) sW2[i] = W2[i];
    if (threadIdx.x < 128) {
        sW1[threadIdx.x] = W1[threadIdx.x];
        sb1[threadIdx.x] = b1[threadIdx.x];
    }
    __syncthreads();
    int n = blockIdx.x * blockDim.x + threadIdx.x;
    if (n >= N) return;
    float sv0 = S[n * 4 + 0], sv1 = S[n * 4 + 1], sv2 = S[n * 4 + 2], sv3 = S[n * 4 + 3];
    float acc[32];
    #pragma unroll
    for (int c = 0; c < 32; ++c) acc[c] = 0.f;
    #pragma unroll
    for (int h = 0; h < 4; ++h) {
        float sh = (h == 0) ? sv0 : (h == 1) ? sv1 : (h == 2) ? sv2 : sv3;
        for (int cc = 0; cc < 32; ++cc) {
            int hc = h * 32 + cc;
            float x1 = fmaf(sh, sW1[hc], sb1[hc]);
            x1 = x1 > 0.f ? x1 : 0.f;
            const float* w2row = &sW2[hc * 32];
            #pragma unroll
            for (int c = 0; c < 32; ++c) acc[c] = fmaf(x1, w2row[c], acc[c]);
        }
    }
    float es = 0.f, edv = 0.f;
    #pragma unroll
    for (int c = 0; c < 32; ++c) {
        es = fmaf(acc[c], a2s[c], es);
        edv = fmaf(acc[c], a2d[c], edv);
    }
    float4* h2v = (float4*)(h2 + (size_t)n * 32);
    #pragma unroll
    for (int q = 0; q < 8; ++q)
        h2v[q] = make_float4(acc[q * 4], acc[q * 4 + 1], acc[q * 4 + 2], acc[q * 4 + 3]);
    es2[n] = es;
    ed2[n] = edv;
}

// ---------------- layer 2 aggregation + fused mean-pool ----------------
// 64 lanes per node: 8 edge-slots x 8 channel-groups (float4 each).
__global__ void k_agg(const float* __restrict__ h2, const float* __restrict__ es2,
                      const float* __restrict__ ed2, const int* __restrict__ rowp,
                      const int* __restrict__ col, const float* __restrict__ b2,
                      const int* __restrict__ batch, float* __restrict__ pooled,
                      float* __restrict__ cnt, int N) {
    int gid = blockIdx.x * blockDim.x + threadIdx.x;
    int n = gid >> 6;               // 64 lanes per node
    int lane = threadIdx.x & 63;
    if (n >= N) return;
    int s = rowp[n];
    int deg = rowp[n + 1] - s;
    float ed = ed2[n];
    // phase A: running max over all incoming edges (64-lane strided)
    float m = NEGBIG;
    for (int i = lane; i < deg; i += 64)
        m = fmaxf(m, LRELU(es2[col[s + i]] + ed));
    #pragma unroll
    for (int o = 32; o; o >>= 1) m = fmaxf(m, __shfl_xor(m, o, 64));
    // phase B: 8 edges in flight; lane = 8*slot + cg, cg covers channels 4cg..4cg+3
    int slot = lane >> 3;
    int cg = lane & 7;
    float4 acc = make_float4(0.f, 0.f, 0.f, 0.f);
    float sump = 0.f;
    for (int j = slot; j < deg; j += 8) {
        int sidx = col[s + j];
        float p = __expf(LRELU(es2[sidx] + ed) - m);
        sump += p;
        float4 hv = *(const float4*)(h2 + (size_t)sidx * 32 + cg * 4);
        acc.x = fmaf(p, hv.x, acc.x);
        acc.y = fmaf(p, hv.y, acc.y);
        acc.z = fmaf(p, hv.z, acc.z);
        acc.w = fmaf(p, hv.w, acc.w);
    }
    // reduce across the 8 edge-slots (partners differ only in slot bits)
    #pragma unroll
    for (int o = 8; o <= 32; o <<= 1) {
        sump += __shfl_xor(sump, o, 64);
        acc.x += __shfl_xor(acc.x, o, 64);
        acc.y += __shfl_xor(acc.y, o, 64);
        acc.z += __shfl_xor(acc.z, o, 64);
        acc.w += __shfl_xor(acc.w, o, 64);
    }
    if (slot == 0) {                // lanes 0..7, each owns 4 channels
        float inv = 1.0f / (sump + 1e-16f);
        int g = batch[n];
        #pragma unroll
        for (int q = 0; q < 4; ++q) {
            int c = cg * 4 + q;
            float v = (q == 0) ? acc.x : (q == 1) ? acc.y : (q == 2) ? acc.z : acc.w;
            float x2 = v * inv + b2[c];
            x2 = x2 > 0.f ? x2 : 0.f;
            atomicAdd(&pooled[g * 32 + c], x2);
        }
        if (cg == 0) atomicAdd(&cnt[g], 1.0f);
    }
}

// ---------------- final: mean, linear, sigmoid ----------------
__global__ void k_final(const float* __restrict__ pooled, const float* __restrict__ cnt,
                        const float* __restrict__ lin_w, const float* __restrict__ lin_b,
                        float* __restrict__ out, int G) {
    int g = blockIdx.x * blockDim.x + threadIdx.x;
    if (g >= G) return;
    float c = fmaxf(cnt[g], 1.0f);
    float acc = 0.f;
    for (int i = 0; i < 32; ++i) acc = fmaf(pooled[g * 32 + i] / c, lin_w[i], acc);
    acc += lin_b[0];
    out[g] = 1.0f / (1.0f + __expf(-acc));
}

extern "C" void kernel_launch(void* const* d_in, const int* in_sizes, int n_in,
                              void* d_out, int out_size, void* d_ws, size_t ws_size,
                              hipStream_t stream) {
    const float* x     = (const float*)d_in[0];
    const int*   ei    = (const int*)d_in[1];
    const int*   batch = (const int*)d_in[2];
    const float* W1    = (const float*)d_in[4];
    const float* a1s   = (const float*)d_in[5];
    const float* a1d   = (const float*)d_in[6];
    const float* b1    = (const float*)d_in[7];
    const float* W2    = (const float*)d_in[8];
    const float* a2s   = (const float*)d_in[9];
    const float* a2d   = (const float*)d_in[10];
    const float* b2    = (const float*)d_in[11];
    const float* lin_w = (const float*)d_in[12];
    const float* lin_b = (const float*)d_in[13];
    float* out = (float*)d_out;

    int N = in_sizes[0];
    int E = in_sizes[1] / 2;
    int ET = E + N;
    int G = out_size;

    char* ws = (char*)d_ws;
    size_t off = 0;
    auto alloc = [&](size_t bytes) -> char* {
        char* p = ws + off;
        off = (off + bytes + 255) & ~(size_t)255;
        return p;
    };
    int*   deg    = (int*)alloc((size_t)N * 4);
    int*   rowp   = (int*)alloc((size_t)(N + 1) * 4);
    int*   cursor = (int*)alloc((size_t)N * 4);
    int*   col    = (int*)alloc((size_t)ET * 4);
    float* S      = (float*)alloc((size_t)N * 16);
    float* h2     = (float*)alloc((size_t)N * 128);
    float* es2    = (float*)alloc((size_t)N * 4);
    float* ed2    = (float*)alloc((size_t)N * 4);
    float* dots   = (float*)alloc(32);
    float* pooled = (float*)alloc((size_t)G * 128);
    float* cnt    = (float*)alloc((size_t)G * 4);

    hipMemsetAsync(deg, 0, (size_t)N * 4, stream);
    hipMemsetAsync(pooled, 0, (size_t)G * 128, stream);
    hipMemsetAsync(cnt, 0, (size_t)G * 4, stream);

    k_hist<<<(ET + 255) / 256, 256, 0, stream>>>(ei, deg, E, N);
    k_scan<<<1, 1024, 0, stream>>>(deg, rowp, cursor, N);
    k_scatter<<<(ET + 255) / 256, 256, 0, stream>>>(ei, cursor, col, E, N);
    k_pre<<<1, 128, 0, stream>>>(W1, a1s, a1d, dots);
    k_layer1<<<(N + 15) / 16, 256, 0, stream>>>(x, rowp, col, dots, S, N);
    k_h2<<<(N + 255) / 256, 256, 0, stream>>>(S, W1, b1, W2, a2s, a2d, h2, es2, ed2, N);
    k_agg<<<((size_t)N * 64 + 255) / 256, 256, 0, stream>>>(h2, es2, ed2, rowp, col, b2, batch, pooled, cnt, N);
    k_final<<<1, 64, 0, stream>>>(pooled, cnt, lin_w, lin_b, out, G);
}

// Round 3
// 517.130 us; speedup vs baseline: 2.7645x; 2.5805x over previous
//
#include <hip/hip_runtime.h>
#include <hip/hip_bf16.h>

#define LRELU(v) ((v) > 0.0f ? (v) : 0.2f * (v))
#define NEGBIG (-3.4e38f)

// ---------------- CSR build ----------------
__global__ void k_hist(const int* __restrict__ ei, int* __restrict__ deg, int E, int N) {
    int e = blockIdx.x * blockDim.x + threadIdx.x;
    if (e >= E + N) return;
    int d = (e < E) ? ei[E + e] : (e - E);
    atomicAdd(&deg[d], 1);
}

__global__ void k_scan(const int* __restrict__ deg, int* __restrict__ rowp,
                       int* __restrict__ cursor, int N) {
    __shared__ int wsum[16];
    int t = threadIdx.x;            // 1024 threads
    int lane = t & 63;
    int w = t >> 6;
    int carry = 0;
    int nch = (N + 1023) >> 10;
    for (int c = 0; c < nch; ++c) {
        int idx = (c << 10) + t;
        int v = (idx < N) ? deg[idx] : 0;
        int sv = v;
        #pragma unroll
        for (int o = 1; o < 64; o <<= 1) {
            int u = __shfl_up(sv, o, 64);
            if (lane >= o) sv += u;
        }
        if (lane == 63) wsum[w] = sv;
        __syncthreads();
        if (t < 16) {
            int ws2 = wsum[t];
            #pragma unroll
            for (int o = 1; o < 16; o <<= 1) {
                int u = __shfl_up(ws2, o, 16);
                if (t >= o) ws2 += u;
            }
            wsum[t] = ws2;
        }
        __syncthreads();
        int woff = (w > 0) ? wsum[w - 1] : 0;
        int excl = sv - v + woff + carry;
        if (idx < N) { rowp[idx] = excl; cursor[idx] = excl; }
        carry += wsum[15];
        __syncthreads();
    }
    if (t == 0) rowp[N] = carry;
}

__global__ void k_scatter(const int* __restrict__ ei, int* __restrict__ cursor,
                          int* __restrict__ col, int E, int N) {
    int e = blockIdx.x * blockDim.x + threadIdx.x;
    if (e >= E + N) return;
    int sN, dN;
    if (e < E) { sN = ei[e]; dN = ei[E + e]; } else { sN = dN = e - E; }
    int pos = atomicAdd(&cursor[dN], 1);
    col[pos] = sN;
}

// ---------------- layer-1 constants ----------------
__global__ void k_pre(const float* __restrict__ W1, const float* __restrict__ a1s,
                      const float* __restrict__ a1d, float* __restrict__ dots) {
    int t = threadIdx.x;            // 128 threads
    float w = W1[t];
    float ps = w * a1s[t];
    float pd = w * a1d[t];
    #pragma unroll
    for (int o = 16; o; o >>= 1) {
        ps += __shfl_xor(ps, o, 32);
        pd += __shfl_xor(pd, o, 32);
    }
    if ((t & 31) == 0) {
        dots[t >> 5] = ps;
        dots[4 + (t >> 5)] = pd;
    }
}

// ---------------- layer 1 ----------------
__global__ void k_layer1(const float* __restrict__ x, const int* __restrict__ rowp,
                         const int* __restrict__ col, const float* __restrict__ dots,
                         float* __restrict__ S, int N) {
    int gid = blockIdx.x * blockDim.x + threadIdx.x;
    int n = gid >> 4;               // 16 lanes per node
    int lane = threadIdx.x & 15;
    if (n >= N) return;
    int s = rowp[n];
    int deg = rowp[n + 1] - s;
    float xd = x[n];
    float ds0 = dots[0], ds1 = dots[1], ds2 = dots[2], ds3 = dots[3];
    float t0 = xd * dots[4], t1 = xd * dots[5], t2 = xd * dots[6], t3 = xd * dots[7];
    float m0 = NEGBIG, m1 = NEGBIG, m2 = NEGBIG, m3 = NEGBIG;
    for (int i = lane; i < deg; i += 16) {
        float xs = x[col[s + i]];
        float e0 = LRELU(fmaf(xs, ds0, t0)); m0 = fmaxf(m0, e0);
        float e1 = LRELU(fmaf(xs, ds1, t1)); m1 = fmaxf(m1, e1);
        float e2 = LRELU(fmaf(xs, ds2, t2)); m2 = fmaxf(m2, e2);
        float e3 = LRELU(fmaf(xs, ds3, t3)); m3 = fmaxf(m3, e3);
    }
    #pragma unroll
    for (int o = 8; o; o >>= 1) {
        m0 = fmaxf(m0, __shfl_xor(m0, o, 16));
        m1 = fmaxf(m1, __shfl_xor(m1, o, 16));
        m2 = fmaxf(m2, __shfl_xor(m2, o, 16));
        m3 = fmaxf(m3, __shfl_xor(m3, o, 16));
    }
    float p0 = 0.f, p1 = 0.f, p2 = 0.f, p3 = 0.f;
    float q0 = 0.f, q1 = 0.f, q2 = 0.f, q3 = 0.f;
    for (int i = lane; i < deg; i += 16) {
        float xs = x[col[s + i]];
        float e0 = __expf(LRELU(fmaf(xs, ds0, t0)) - m0); p0 += e0; q0 = fmaf(e0, xs, q0);
        float e1 = __expf(LRELU(fmaf(xs, ds1, t1)) - m1); p1 += e1; q1 = fmaf(e1, xs, q1);
        float e2 = __expf(LRELU(fmaf(xs, ds2, t2)) - m2); p2 += e2; q2 = fmaf(e2, xs, q2);
        float e3 = __expf(LRELU(fmaf(xs, ds3, t3)) - m3); p3 += e3; q3 = fmaf(e3, xs, q3);
    }
    #pragma unroll
    for (int o = 8; o; o >>= 1) {
        p0 += __shfl_xor(p0, o, 16); p1 += __shfl_xor(p1, o, 16);
        p2 += __shfl_xor(p2, o, 16); p3 += __shfl_xor(p3, o, 16);
        q0 += __shfl_xor(q0, o, 16); q1 += __shfl_xor(q1, o, 16);
        q2 += __shfl_xor(q2, o, 16); q3 += __shfl_xor(q3, o, 16);
    }
    if (lane == 0) {
        float4 r;
        r.x = q0 / (p0 + 1e-16f);
        r.y = q1 / (p1 + 1e-16f);
        r.z = q2 / (p2 + 1e-16f);
        r.w = q3 / (p3 + 1e-16f);
        *(float4*)(S + n * 4) = r;
    }
}

// ---------------- layer 2 node transform ----------------
__global__ void k_h2(const float* __restrict__ S, const float* __restrict__ W1,
                     const float* __restrict__ b1, const float* __restrict__ W2,
                     const float* __restrict__ a2s, const float* __restrict__ a2d,
                     float* __restrict__ h2, float* __restrict__ es2,
                     float* __restrict__ ed2, int N) {
    __shared__ float sW2[4096];
    __shared__ float sW1[128];
    __shared__ float sb1[128];
    for (int i = threadIdx.x; i < 4096; i += blockDim.x) sW2[i] = W2[i];
    if (threadIdx.x < 128) {
        sW1[threadIdx.x] = W1[threadIdx.x];
        sb1[threadIdx.x] = b1[threadIdx.x];
    }
    __syncthreads();
    int n = blockIdx.x * blockDim.x + threadIdx.x;
    if (n >= N) return;
    float sv0 = S[n * 4 + 0], sv1 = S[n * 4 + 1], sv2 = S[n * 4 + 2], sv3 = S[n * 4 + 3];
    float acc[32];
    #pragma unroll
    for (int c = 0; c < 32; ++c) acc[c] = 0.f;
    #pragma unroll
    for (int h = 0; h < 4; ++h) {
        float sh = (h == 0) ? sv0 : (h == 1) ? sv1 : (h == 2) ? sv2 : sv3;
        for (int cc = 0; cc < 32; ++cc) {
            int hc = h * 32 + cc;
            float x1 = fmaf(sh, sW1[hc], sb1[hc]);
            x1 = x1 > 0.f ? x1 : 0.f;
            const float* w2row = &sW2[hc * 32];
            #pragma unroll
            for (int c = 0; c < 32; ++c) acc[c] = fmaf(x1, w2row[c], acc[c]);
        }
    }
    float es = 0.f, edv = 0.f;
    #pragma unroll
    for (int c = 0; c < 32; ++c) {
        es = fmaf(acc[c], a2s[c], es);
        edv = fmaf(acc[c], a2d[c], edv);
    }
    float4* h2v = (float4*)(h2 + (size_t)n * 32);
    #pragma unroll
    for (int q = 0; q < 8; ++q)
        h2v[q] = make_float4(acc[q * 4], acc[q * 4 + 1], acc[q * 4 + 2], acc[q * 4 + 3]);
    es2[n] = es;
    ed2[n] = edv;
}

// ---------------- layer 2 aggregation: per-node x2 row, NO atomics ----------------
// 64 lanes per node: 8 edge-slots x 8 channel-groups (float4 each).
__global__ void k_agg(const float* __restrict__ h2, const float* __restrict__ es2,
                      const float* __restrict__ ed2, const int* __restrict__ rowp,
                      const int* __restrict__ col, const float* __restrict__ b2,
                      float* __restrict__ x2buf, int N) {
    int gid = blockIdx.x * blockDim.x + threadIdx.x;
    int n = gid >> 6;               // 64 lanes per node
    int lane = threadIdx.x & 63;
    if (n >= N) return;
    int s = rowp[n];
    int deg = rowp[n + 1] - s;
    float ed = ed2[n];
    // phase A: running max over all incoming edges (64-lane strided)
    float m = NEGBIG;
    for (int i = lane; i < deg; i += 64)
        m = fmaxf(m, LRELU(es2[col[s + i]] + ed));
    #pragma unroll
    for (int o = 32; o; o >>= 1) m = fmaxf(m, __shfl_xor(m, o, 64));
    // phase B: 8 edges in flight; lane = 8*slot + cg, cg covers channels 4cg..4cg+3
    int slot = lane >> 3;
    int cg = lane & 7;
    float4 acc = make_float4(0.f, 0.f, 0.f, 0.f);
    float sump = 0.f;
    for (int j = slot; j < deg; j += 8) {
        int sidx = col[s + j];
        float p = __expf(LRELU(es2[sidx] + ed) - m);
        sump += p;
        float4 hv = *(const float4*)(h2 + (size_t)sidx * 32 + cg * 4);
        acc.x = fmaf(p, hv.x, acc.x);
        acc.y = fmaf(p, hv.y, acc.y);
        acc.z = fmaf(p, hv.z, acc.z);
        acc.w = fmaf(p, hv.w, acc.w);
    }
    // reduce across the 8 edge-slots (slot bits are lane bits 3,4,5)
    #pragma unroll
    for (int o = 8; o <= 32; o <<= 1) {
        sump += __shfl_xor(sump, o, 64);
        acc.x += __shfl_xor(acc.x, o, 64);
        acc.y += __shfl_xor(acc.y, o, 64);
        acc.z += __shfl_xor(acc.z, o, 64);
        acc.w += __shfl_xor(acc.w, o, 64);
    }
    if (slot == 0) {                // lanes 0..7, each owns channels 4cg..4cg+3
        float inv = 1.0f / (sump + 1e-16f);
        float4 bv = *(const float4*)(b2 + cg * 4);
        float4 r;
        r.x = fmaf(acc.x, inv, bv.x); r.x = r.x > 0.f ? r.x : 0.f;
        r.y = fmaf(acc.y, inv, bv.y); r.y = r.y > 0.f ? r.y : 0.f;
        r.z = fmaf(acc.z, inv, bv.z); r.z = r.z > 0.f ? r.z : 0.f;
        r.w = fmaf(acc.w, inv, bv.w); r.w = r.w > 0.f ? r.w : 0.f;
        *(float4*)(x2buf + (size_t)n * 32 + cg * 4) = r;
    }
}

// ---------------- pooling + head: one block per graph, no atomics ----------------
__global__ void k_pool(const float* __restrict__ x2buf, const int* __restrict__ batch,
                       const float* __restrict__ lin_w, const float* __restrict__ lin_b,
                       float* __restrict__ out, int N) {
    int g = blockIdx.x;
    __shared__ int sr[2];
    if (threadIdx.x == 0) {
        int lo = 0, hi = N;
        while (lo < hi) { int mid = (lo + hi) >> 1; if (batch[mid] < g) lo = mid + 1; else hi = mid; }
        sr[0] = lo;
        int l2 = lo, h2v = N;
        while (l2 < h2v) { int mid = (l2 + h2v) >> 1; if (batch[mid] < g + 1) l2 = mid + 1; else h2v = mid; }
        sr[1] = l2;
    }
    __syncthreads();
    int lo = sr[0], hi = sr[1];
    int ch = threadIdx.x & 31;      // channel
    int slot = threadIdx.x >> 5;    // 8 node slots
    float acc = 0.f;
    for (int n = lo + slot; n < hi; n += 8)
        acc += x2buf[(size_t)n * 32 + ch];
    __shared__ float red[256];
    red[threadIdx.x] = acc;
    __syncthreads();
    #pragma unroll
    for (int o = 128; o >= 32; o >>= 1) {
        if (threadIdx.x < o) red[threadIdx.x] += red[threadIdx.x + o];
        __syncthreads();
    }
    if (threadIdx.x < 32) {
        float c = fmaxf((float)(hi - lo), 1.0f);
        float v = red[threadIdx.x] / c * lin_w[threadIdx.x];
        #pragma unroll
        for (int o = 16; o; o >>= 1) v += __shfl_xor(v, o, 32);
        if (threadIdx.x == 0) out[g] = 1.0f / (1.0f + __expf(-(v + lin_b[0])));
    }
}

extern "C" void kernel_launch(void* const* d_in, const int* in_sizes, int n_in,
                              void* d_out, int out_size, void* d_ws, size_t ws_size,
                              hipStream_t stream) {
    const float* x     = (const float*)d_in[0];
    const int*   ei    = (const int*)d_in[1];
    const int*   batch = (const int*)d_in[2];
    const float* W1    = (const float*)d_in[4];
    const float* a1s   = (const float*)d_in[5];
    const float* a1d   = (const float*)d_in[6];
    const float* b1    = (const float*)d_in[7];
    const float* W2    = (const float*)d_in[8];
    const float* a2s   = (const float*)d_in[9];
    const float* a2d   = (const float*)d_in[10];
    const float* b2    = (const float*)d_in[11];
    const float* lin_w = (const float*)d_in[12];
    const float* lin_b = (const float*)d_in[13];
    float* out = (float*)d_out;

    int N = in_sizes[0];
    int E = in_sizes[1] / 2;
    int ET = E + N;
    int G = out_size;

    char* ws = (char*)d_ws;
    size_t off = 0;
    auto alloc = [&](size_t bytes) -> char* {
        char* p = ws + off;
        off = (off + bytes + 255) & ~(size_t)255;
        return p;
    };
    int*   deg    = (int*)alloc((size_t)N * 4);
    int*   rowp   = (int*)alloc((size_t)(N + 1) * 4);
    int*   cursor = (int*)alloc((size_t)N * 4);
    int*   col    = (int*)alloc((size_t)ET * 4);
    float* S      = (float*)alloc((size_t)N * 16);
    float* h2     = (float*)alloc((size_t)N * 128);
    float* es2    = (float*)alloc((size_t)N * 4);
    float* ed2    = (float*)alloc((size_t)N * 4);
    float* dots   = (float*)alloc(32);
    float* x2buf  = (float*)alloc((size_t)N * 128);

    hipMemsetAsync(deg, 0, (size_t)N * 4, stream);

    k_hist<<<(ET + 255) / 256, 256, 0, stream>>>(ei, deg, E, N);
    k_scan<<<1, 1024, 0, stream>>>(deg, rowp, cursor, N);
    k_scatter<<<(ET + 255) / 256, 256, 0, stream>>>(ei, cursor, col, E, N);
    k_pre<<<1, 128, 0, stream>>>(W1, a1s, a1d, dots);
    k_layer1<<<(N + 15) / 16, 256, 0, stream>>>(x, rowp, col, dots, S, N);
    k_h2<<<(N + 255) / 256, 256, 0, stream>>>(S, W1, b1, W2, a2s, a2d, h2, es2, ed2, N);
    k_agg<<<((size_t)N * 64 + 255) / 256, 256, 0, stream>>>(h2, es2, ed2, rowp, col, b2, x2buf, N);
    k_pool<<<G, 256, 0, stream>>>(x2buf, batch, lin_w, lin_b, out, N);
}

// Round 4
// 238.370 us; speedup vs baseline: 5.9973x; 2.1694x over previous
//
#include <hip/hip_runtime.h>
#include <hip/hip_bf16.h>

#define LRELU(v) ((v) > 0.0f ? (v) : 0.2f * (v))
#define NEGBIG (-3.4e38f)

// ================= CSR build via dst-bucket sort (128 dst-nodes per bucket) =================
// Pass 1: per-block LDS histogram -> global bucket counts (low-contention atomics)
__global__ void k_cnt(const int* __restrict__ ei, int* __restrict__ bucket_cnt,
                      int E, int N, int nb) {
    __shared__ int h[1024];
    for (int i = threadIdx.x; i < nb; i += 256) h[i] = 0;
    __syncthreads();
    int ET = E + N;
    int base = blockIdx.x * 8192;
    int end = base + 8192 < ET ? base + 8192 : ET;
    for (int e = base + threadIdx.x; e < end; e += 256) {
        int d = (e < E) ? ei[E + e] : (e - E);
        atomicAdd(&h[d >> 7], 1);
    }
    __syncthreads();
    for (int i = threadIdx.x; i < nb; i += 256)
        if (h[i]) atomicAdd(&bucket_cnt[i], h[i]);
}

// Pass 2: scan bucket counts (nb <= 1024) -> bucket_start, init bucket_cursor
__global__ void k_scanB(const int* __restrict__ bucket_cnt, int* __restrict__ bucket_start,
                        int* __restrict__ bucket_cursor, int nb) {
    __shared__ int wsum[16];
    int t = threadIdx.x;            // 1024 threads
    int v = (t < nb) ? bucket_cnt[t] : 0;
    int lane = t & 63, w = t >> 6;
    int sv = v;
    #pragma unroll
    for (int o = 1; o < 64; o <<= 1) {
        int u = __shfl_up(sv, o, 64);
        if (lane >= o) sv += u;
    }
    if (lane == 63) wsum[w] = sv;
    __syncthreads();
    if (t < 16) {
        int ws2 = wsum[t];
        #pragma unroll
        for (int o = 1; o < 16; o <<= 1) {
            int u = __shfl_up(ws2, o, 16);
            if (t >= o) ws2 += u;
        }
        wsum[t] = ws2;
    }
    __syncthreads();
    int excl = sv - v + (w ? wsum[w - 1] : 0);
    if (t < nb) { bucket_start[t] = excl; bucket_cursor[t] = excl; }
    if (t == nb - 1) bucket_start[nb] = excl + v;
}

// Pass 3: per-block reserve ranges per bucket, append packed (src<<7 | dstlocal)
__global__ void k_scat(const int* __restrict__ ei, int* __restrict__ bucket_cursor,
                       int* __restrict__ pairbuf, int E, int N, int nb) {
    __shared__ int h[1024];
    __shared__ int basearr[1024];
    for (int i = threadIdx.x; i < nb; i += 256) h[i] = 0;
    __syncthreads();
    int ET = E + N;
    int base = blockIdx.x * 8192;
    int end = base + 8192 < ET ? base + 8192 : ET;
    for (int e = base + threadIdx.x; e < end; e += 256) {
        int d = (e < E) ? ei[E + e] : (e - E);
        atomicAdd(&h[d >> 7], 1);
    }
    __syncthreads();
    for (int i = threadIdx.x; i < nb; i += 256) {
        int c = h[i];
        basearr[i] = c ? atomicAdd(&bucket_cursor[i], c) : 0;
        h[i] = 0;
    }
    __syncthreads();
    for (int e = base + threadIdx.x; e < end; e += 256) {
        int s, d;
        if (e < E) { s = ei[e]; d = ei[E + e]; } else { s = d = e - E; }
        int b = d >> 7;
        int pos = basearr[b] + atomicAdd(&h[b], 1);
        pairbuf[pos] = (s << 7) | (d & 127);
    }
}

// Pass 4: one block per bucket -> rowp + col (all scatters inside an L1-resident window)
__global__ void k_build(const int* __restrict__ pairbuf, const int* __restrict__ bucket_start,
                        int* __restrict__ rowp, int* __restrict__ col, int N, int nb) {
    int b = blockIdx.x;
    __shared__ int deg[128];
    __shared__ int inc[128];
    __shared__ int rbase[128];
    __shared__ int cur[128];
    int s0 = bucket_start[b], s1 = bucket_start[b + 1];
    if (threadIdx.x < 128) deg[threadIdx.x] = 0;
    __syncthreads();
    for (int i = s0 + threadIdx.x; i < s1; i += 256)
        atomicAdd(&deg[pairbuf[i] & 127], 1);
    __syncthreads();
    if (threadIdx.x < 128) {
        int lane = threadIdx.x & 63;
        int sv = deg[threadIdx.x];
        #pragma unroll
        for (int o = 1; o < 64; o <<= 1) {
            int u = __shfl_up(sv, o, 64);
            if (lane >= o) sv += u;
        }
        inc[threadIdx.x] = sv;
    }
    __syncthreads();
    if (threadIdx.x < 128) {
        int excl = inc[threadIdx.x] - deg[threadIdx.x] + ((threadIdx.x >= 64) ? inc[63] : 0);
        rbase[threadIdx.x] = s0 + excl;
        cur[threadIdx.x] = 0;
        int node = (b << 7) + threadIdx.x;
        if (node < N) rowp[node] = s0 + excl;
    }
    __syncthreads();
    for (int i = s0 + threadIdx.x; i < s1; i += 256) {
        int p = pairbuf[i];
        int off = p & 127;
        int pos = rbase[off] + atomicAdd(&cur[off], 1);
        col[pos] = p >> 7;
    }
    if (b == 0 && threadIdx.x == 0) rowp[N] = bucket_start[nb];
}

// ---------------- layer-1 constants ----------------
__global__ void k_pre(const float* __restrict__ W1, const float* __restrict__ a1s,
                      const float* __restrict__ a1d, float* __restrict__ dots) {
    int t = threadIdx.x;            // 128 threads
    float w = W1[t];
    float ps = w * a1s[t];
    float pd = w * a1d[t];
    #pragma unroll
    for (int o = 16; o; o >>= 1) {
        ps += __shfl_xor(ps, o, 32);
        pd += __shfl_xor(pd, o, 32);
    }
    if ((t & 31) == 0) {
        dots[t >> 5] = ps;
        dots[4 + (t >> 5)] = pd;
    }
}

// ---------------- layer 1 ----------------
__global__ void k_layer1(const float* __restrict__ x, const int* __restrict__ rowp,
                         const int* __restrict__ col, const float* __restrict__ dots,
                         float* __restrict__ S, int N) {
    int gid = blockIdx.x * blockDim.x + threadIdx.x;
    int n = gid >> 4;               // 16 lanes per node
    int lane = threadIdx.x & 15;
    if (n >= N) return;
    int s = rowp[n];
    int deg = rowp[n + 1] - s;
    float xd = x[n];
    float ds0 = dots[0], ds1 = dots[1], ds2 = dots[2], ds3 = dots[3];
    float t0 = xd * dots[4], t1 = xd * dots[5], t2 = xd * dots[6], t3 = xd * dots[7];
    float m0 = NEGBIG, m1 = NEGBIG, m2 = NEGBIG, m3 = NEGBIG;
    for (int i = lane; i < deg; i += 16) {
        float xs = x[col[s + i]];
        float e0 = LRELU(fmaf(xs, ds0, t0)); m0 = fmaxf(m0, e0);
        float e1 = LRELU(fmaf(xs, ds1, t1)); m1 = fmaxf(m1, e1);
        float e2 = LRELU(fmaf(xs, ds2, t2)); m2 = fmaxf(m2, e2);
        float e3 = LRELU(fmaf(xs, ds3, t3)); m3 = fmaxf(m3, e3);
    }
    #pragma unroll
    for (int o = 8; o; o >>= 1) {
        m0 = fmaxf(m0, __shfl_xor(m0, o, 16));
        m1 = fmaxf(m1, __shfl_xor(m1, o, 16));
        m2 = fmaxf(m2, __shfl_xor(m2, o, 16));
        m3 = fmaxf(m3, __shfl_xor(m3, o, 16));
    }
    float p0 = 0.f, p1 = 0.f, p2 = 0.f, p3 = 0.f;
    float q0 = 0.f, q1 = 0.f, q2 = 0.f, q3 = 0.f;
    for (int i = lane; i < deg; i += 16) {
        float xs = x[col[s + i]];
        float e0 = __expf(LRELU(fmaf(xs, ds0, t0)) - m0); p0 += e0; q0 = fmaf(e0, xs, q0);
        float e1 = __expf(LRELU(fmaf(xs, ds1, t1)) - m1); p1 += e1; q1 = fmaf(e1, xs, q1);
        float e2 = __expf(LRELU(fmaf(xs, ds2, t2)) - m2); p2 += e2; q2 = fmaf(e2, xs, q2);
        float e3 = __expf(LRELU(fmaf(xs, ds3, t3)) - m3); p3 += e3; q3 = fmaf(e3, xs, q3);
    }
    #pragma unroll
    for (int o = 8; o; o >>= 1) {
        p0 += __shfl_xor(p0, o, 16); p1 += __shfl_xor(p1, o, 16);
        p2 += __shfl_xor(p2, o, 16); p3 += __shfl_xor(p3, o, 16);
        q0 += __shfl_xor(q0, o, 16); q1 += __shfl_xor(q1, o, 16);
        q2 += __shfl_xor(q2, o, 16); q3 += __shfl_xor(q3, o, 16);
    }
    if (lane == 0) {
        float4 r;
        r.x = q0 / (p0 + 1e-16f);
        r.y = q1 / (p1 + 1e-16f);
        r.z = q2 / (p2 + 1e-16f);
        r.w = q3 / (p3 + 1e-16f);
        *(float4*)(S + n * 4) = r;
    }
}

// ---------------- layer 2 node transform ----------------
__global__ void k_h2(const float* __restrict__ S, const float* __restrict__ W1,
                     const float* __restrict__ b1, const float* __restrict__ W2,
                     const float* __restrict__ a2s, const float* __restrict__ a2d,
                     float* __restrict__ h2, float* __restrict__ es2,
                     float* __restrict__ ed2, int N) {
    __shared__ float sW2[4096];
    __shared__ float sW1[128];
    __shared__ float sb1[128];
    for (int i = threadIdx.x; i < 4096; i += blockDim.x) sW2[i] = W2[i];
    if (threadIdx.x < 128) {
        sW1[threadIdx.x] = W1[threadIdx.x];
        sb1[threadIdx.x] = b1[threadIdx.x];
    }
    __syncthreads();
    int n = blockIdx.x * blockDim.x + threadIdx.x;
    if (n >= N) return;
    float sv0 = S[n * 4 + 0], sv1 = S[n * 4 + 1], sv2 = S[n * 4 + 2], sv3 = S[n * 4 + 3];
    float acc[32];
    #pragma unroll
    for (int c = 0; c < 32; ++c) acc[c] = 0.f;
    #pragma unroll
    for (int h = 0; h < 4; ++h) {
        float sh = (h == 0) ? sv0 : (h == 1) ? sv1 : (h == 2) ? sv2 : sv3;
        for (int cc = 0; cc < 32; ++cc) {
            int hc = h * 32 + cc;
            float x1 = fmaf(sh, sW1[hc], sb1[hc]);
            x1 = x1 > 0.f ? x1 : 0.f;
            const float* w2row = &sW2[hc * 32];
            #pragma unroll
            for (int c = 0; c < 32; ++c) acc[c] = fmaf(x1, w2row[c], acc[c]);
        }
    }
    float es = 0.f, edv = 0.f;
    #pragma unroll
    for (int c = 0; c < 32; ++c) {
        es = fmaf(acc[c], a2s[c], es);
        edv = fmaf(acc[c], a2d[c], edv);
    }
    float4* h2v = (float4*)(h2 + (size_t)n * 32);
    #pragma unroll
    for (int q = 0; q < 8; ++q)
        h2v[q] = make_float4(acc[q * 4], acc[q * 4 + 1], acc[q * 4 + 2], acc[q * 4 + 3]);
    es2[n] = es;
    ed2[n] = edv;
}

// ---------------- layer 2 aggregation: per-node x2 row, NO atomics ----------------
__global__ void k_agg(const float* __restrict__ h2, const float* __restrict__ es2,
                      const float* __restrict__ ed2, const int* __restrict__ rowp,
                      const int* __restrict__ col, const float* __restrict__ b2,
                      float* __restrict__ x2buf, int N) {
    int gid = blockIdx.x * blockDim.x + threadIdx.x;
    int n = gid >> 6;               // 64 lanes per node
    int lane = threadIdx.x & 63;
    if (n >= N) return;
    int s = rowp[n];
    int deg = rowp[n + 1] - s;
    float ed = ed2[n];
    float m = NEGBIG;
    for (int i = lane; i < deg; i += 64)
        m = fmaxf(m, LRELU(es2[col[s + i]] + ed));
    #pragma unroll
    for (int o = 32; o; o >>= 1) m = fmaxf(m, __shfl_xor(m, o, 64));
    int slot = lane >> 3;
    int cg = lane & 7;
    float4 acc = make_float4(0.f, 0.f, 0.f, 0.f);
    float sump = 0.f;
    for (int j = slot; j < deg; j += 8) {
        int sidx = col[s + j];
        float p = __expf(LRELU(es2[sidx] + ed) - m);
        sump += p;
        float4 hv = *(const float4*)(h2 + (size_t)sidx * 32 + cg * 4);
        acc.x = fmaf(p, hv.x, acc.x);
        acc.y = fmaf(p, hv.y, acc.y);
        acc.z = fmaf(p, hv.z, acc.z);
        acc.w = fmaf(p, hv.w, acc.w);
    }
    #pragma unroll
    for (int o = 8; o <= 32; o <<= 1) {
        sump += __shfl_xor(sump, o, 64);
        acc.x += __shfl_xor(acc.x, o, 64);
        acc.y += __shfl_xor(acc.y, o, 64);
        acc.z += __shfl_xor(acc.z, o, 64);
        acc.w += __shfl_xor(acc.w, o, 64);
    }
    if (slot == 0) {
        float inv = 1.0f / (sump + 1e-16f);
        float4 bv = *(const float4*)(b2 + cg * 4);
        float4 r;
        r.x = fmaf(acc.x, inv, bv.x); r.x = r.x > 0.f ? r.x : 0.f;
        r.y = fmaf(acc.y, inv, bv.y); r.y = r.y > 0.f ? r.y : 0.f;
        r.z = fmaf(acc.z, inv, bv.z); r.z = r.z > 0.f ? r.z : 0.f;
        r.w = fmaf(acc.w, inv, bv.w); r.w = r.w > 0.f ? r.w : 0.f;
        *(float4*)(x2buf + (size_t)n * 32 + cg * 4) = r;
    }
}

// ---------------- pooling + head: one block per graph, no atomics ----------------
__global__ void k_pool(const float* __restrict__ x2buf, const int* __restrict__ batch,
                       const float* __restrict__ lin_w, const float* __restrict__ lin_b,
                       float* __restrict__ out, int N) {
    int g = blockIdx.x;
    __shared__ int sr[2];
    if (threadIdx.x == 0) {
        int lo = 0, hi = N;
        while (lo < hi) { int mid = (lo + hi) >> 1; if (batch[mid] < g) lo = mid + 1; else hi = mid; }
        sr[0] = lo;
        int l2 = lo, h2v = N;
        while (l2 < h2v) { int mid = (l2 + h2v) >> 1; if (batch[mid] < g + 1) l2 = mid + 1; else h2v = mid; }
        sr[1] = l2;
    }
    __syncthreads();
    int lo = sr[0], hi = sr[1];
    int ch = threadIdx.x & 31;
    int slot = threadIdx.x >> 5;
    float acc = 0.f;
    for (int n = lo + slot; n < hi; n += 8)
        acc += x2buf[(size_t)n * 32 + ch];
    __shared__ float red[256];
    red[threadIdx.x] = acc;
    __syncthreads();
    #pragma unroll
    for (int o = 128; o >= 32; o >>= 1) {
        if (threadIdx.x < o) red[threadIdx.x] += red[threadIdx.x + o];
        __syncthreads();
    }
    if (threadIdx.x < 32) {
        float c = fmaxf((float)(hi - lo), 1.0f);
        float v = red[threadIdx.x] / c * lin_w[threadIdx.x];
        #pragma unroll
        for (int o = 16; o; o >>= 1) v += __shfl_xor(v, o, 32);
        if (threadIdx.x == 0) out[g] = 1.0f / (1.0f + __expf(-(v + lin_b[0])));
    }
}

extern "C" void kernel_launch(void* const* d_in, const int* in_sizes, int n_in,
                              void* d_out, int out_size, void* d_ws, size_t ws_size,
                              hipStream_t stream) {
    const float* x     = (const float*)d_in[0];
    const int*   ei    = (const int*)d_in[1];
    const int*   batch = (const int*)d_in[2];
    const float* W1    = (const float*)d_in[4];
    const float* a1s   = (const float*)d_in[5];
    const float* a1d   = (const float*)d_in[6];
    const float* b1    = (const float*)d_in[7];
    const float* W2    = (const float*)d_in[8];
    const float* a2s   = (const float*)d_in[9];
    const float* a2d   = (const float*)d_in[10];
    const float* b2    = (const float*)d_in[11];
    const float* lin_w = (const float*)d_in[12];
    const float* lin_b = (const float*)d_in[13];
    float* out = (float*)d_out;

    int N = in_sizes[0];
    int E = in_sizes[1] / 2;
    int ET = E + N;
    int G = out_size;
    int nb = (N + 127) >> 7;        // dst-buckets of 128 nodes (<=1024 for N<=131072)

    char* ws = (char*)d_ws;
    size_t off = 0;
    auto alloc = [&](size_t bytes) -> char* {
        char* p = ws + off;
        off = (off + bytes + 255) & ~(size_t)255;
        return p;
    };
    int*   bucket_cnt    = (int*)alloc(1024 * 4);
    int*   bucket_start  = (int*)alloc(1025 * 4);
    int*   bucket_cursor = (int*)alloc(1024 * 4);
    int*   pairbuf = (int*)alloc((size_t)ET * 4);
    int*   rowp    = (int*)alloc((size_t)(N + 1) * 4);
    int*   col     = (int*)alloc((size_t)ET * 4);
    float* S       = (float*)alloc((size_t)N * 16);
    float* h2      = (float*)alloc((size_t)N * 128);
    float* es2     = (float*)alloc((size_t)N * 4);
    float* ed2     = (float*)alloc((size_t)N * 4);
    float* dots    = (float*)alloc(32);
    float* x2buf   = (float*)alloc((size_t)N * 128);

    hipMemsetAsync(bucket_cnt, 0, (size_t)nb * 4, stream);

    int nblk = (ET + 8191) / 8192;
    k_cnt<<<nblk, 256, 0, stream>>>(ei, bucket_cnt, E, N, nb);
    k_scanB<<<1, 1024, 0, stream>>>(bucket_cnt, bucket_start, bucket_cursor, nb);
    k_scat<<<nblk, 256, 0, stream>>>(ei, bucket_cursor, pairbuf, E, N, nb);
    k_build<<<nb, 256, 0, stream>>>(pairbuf, bucket_start, rowp, col, N, nb);
    k_pre<<<1, 128, 0, stream>>>(W1, a1s, a1d, dots);
    k_layer1<<<(N + 15) / 16, 256, 0, stream>>>(x, rowp, col, dots, S, N);
    k_h2<<<(N + 255) / 256, 256, 0, stream>>>(S, W1, b1, W2, a2s, a2d, h2, es2, ed2, N);
    k_agg<<<((size_t)N * 64 + 255) / 256, 256, 0, stream>>>(h2, es2, ed2, rowp, col, b2, x2buf, N);
    k_pool<<<G, 256, 0, stream>>>(x2buf, batch, lin_w, lin_b, out, N);
}

// Round 5
// 225.536 us; speedup vs baseline: 6.3386x; 1.0569x over previous
//
#include <hip/hip_runtime.h>
#include <hip/hip_bf16.h>

#define LRELU(v) ((v) > 0.0f ? (v) : 0.2f * (v))
#define NEGBIG (-3.4e38f)

__device__ __forceinline__ unsigned short f2bf(float f) {
    unsigned int u = __float_as_uint(f);
    unsigned int r = (u >> 16) & 1;
    u += 0x7fff + r;                 // round-to-nearest-even
    return (unsigned short)(u >> 16);
}
__device__ __forceinline__ float bfl(unsigned int u) {  // low bf16 of a uint32
    return __uint_as_float(u << 16);
}
__device__ __forceinline__ float bfh(unsigned int u) {  // high bf16 of a uint32
    return __uint_as_float(u & 0xffff0000u);
}

// ================= CSR build via dst-bucket sort (128 dst-nodes per bucket) =================
__global__ void k_cnt(const int* __restrict__ ei, int* __restrict__ bucket_cnt,
                      int E, int N, int nb) {
    __shared__ int h[1024];
    for (int i = threadIdx.x; i < nb; i += 256) h[i] = 0;
    __syncthreads();
    int ET = E + N;
    int base = blockIdx.x * 8192;
    int end = base + 8192 < ET ? base + 8192 : ET;
    for (int e = base + threadIdx.x; e < end; e += 256) {
        int d = (e < E) ? ei[E + e] : (e - E);
        atomicAdd(&h[d >> 7], 1);
    }
    __syncthreads();
    for (int i = threadIdx.x; i < nb; i += 256)
        if (h[i]) atomicAdd(&bucket_cnt[i], h[i]);
}

__global__ void k_scanB(const int* __restrict__ bucket_cnt, int* __restrict__ bucket_start,
                        int* __restrict__ bucket_cursor, int nb) {
    __shared__ int wsum[16];
    int t = threadIdx.x;            // 1024 threads
    int v = (t < nb) ? bucket_cnt[t] : 0;
    int lane = t & 63, w = t >> 6;
    int sv = v;
    #pragma unroll
    for (int o = 1; o < 64; o <<= 1) {
        int u = __shfl_up(sv, o, 64);
        if (lane >= o) sv += u;
    }
    if (lane == 63) wsum[w] = sv;
    __syncthreads();
    if (t < 16) {
        int ws2 = wsum[t];
        #pragma unroll
        for (int o = 1; o < 16; o <<= 1) {
            int u = __shfl_up(ws2, o, 16);
            if (t >= o) ws2 += u;
        }
        wsum[t] = ws2;
    }
    __syncthreads();
    int excl = sv - v + (w ? wsum[w - 1] : 0);
    if (t < nb) { bucket_start[t] = excl; bucket_cursor[t] = excl; }
    if (t == nb - 1) bucket_start[nb] = excl + v;
}

__global__ void k_scat(const int* __restrict__ ei, int* __restrict__ bucket_cursor,
                       int* __restrict__ pairbuf, int E, int N, int nb) {
    __shared__ int h[1024];
    __shared__ int basearr[1024];
    for (int i = threadIdx.x; i < nb; i += 256) h[i] = 0;
    __syncthreads();
    int ET = E + N;
    int base = blockIdx.x * 8192;
    int end = base + 8192 < ET ? base + 8192 : ET;
    for (int e = base + threadIdx.x; e < end; e += 256) {
        int d = (e < E) ? ei[E + e] : (e - E);
        atomicAdd(&h[d >> 7], 1);
    }
    __syncthreads();
    for (int i = threadIdx.x; i < nb; i += 256) {
        int c = h[i];
        basearr[i] = c ? atomicAdd(&bucket_cursor[i], c) : 0;
        h[i] = 0;
    }
    __syncthreads();
    for (int e = base + threadIdx.x; e < end; e += 256) {
        int s, d;
        if (e < E) { s = ei[e]; d = ei[E + e]; } else { s = d = e - E; }
        int b = d >> 7;
        int pos = basearr[b] + atomicAdd(&h[b], 1);
        pairbuf[pos] = (s << 7) | (d & 127);
    }
}

__global__ void k_build(const int* __restrict__ pairbuf, const int* __restrict__ bucket_start,
                        int* __restrict__ rowp, int* __restrict__ col, int N, int nb) {
    int b = blockIdx.x;
    __shared__ int deg[128];
    __shared__ int inc[128];
    __shared__ int rbase[128];
    __shared__ int cur[128];
    int s0 = bucket_start[b], s1 = bucket_start[b + 1];
    if (threadIdx.x < 128) deg[threadIdx.x] = 0;
    __syncthreads();
    for (int i = s0 + threadIdx.x; i < s1; i += 256)
        atomicAdd(&deg[pairbuf[i] & 127], 1);
    __syncthreads();
    if (threadIdx.x < 128) {
        int lane = threadIdx.x & 63;
        int sv = deg[threadIdx.x];
        #pragma unroll
        for (int o = 1; o < 64; o <<= 1) {
            int u = __shfl_up(sv, o, 64);
            if (lane >= o) sv += u;
        }
        inc[threadIdx.x] = sv;
    }
    __syncthreads();
    if (threadIdx.x < 128) {
        int excl = inc[threadIdx.x] - deg[threadIdx.x] + ((threadIdx.x >= 64) ? inc[63] : 0);
        rbase[threadIdx.x] = s0 + excl;
        cur[threadIdx.x] = 0;
        int node = (b << 7) + threadIdx.x;
        if (node < N) rowp[node] = s0 + excl;
    }
    __syncthreads();
    for (int i = s0 + threadIdx.x; i < s1; i += 256) {
        int p = pairbuf[i];
        int off = p & 127;
        int pos = rbase[off] + atomicAdd(&cur[off], 1);
        col[pos] = p >> 7;
    }
    if (b == 0 && threadIdx.x == 0) rowp[N] = bucket_start[nb];
}

// ---------------- layer-1 constants ----------------
__global__ void k_pre(const float* __restrict__ W1, const float* __restrict__ a1s,
                      const float* __restrict__ a1d, float* __restrict__ dots) {
    int t = threadIdx.x;            // 128 threads
    float w = W1[t];
    float ps = w * a1s[t];
    float pd = w * a1d[t];
    #pragma unroll
    for (int o = 16; o; o >>= 1) {
        ps += __shfl_xor(ps, o, 32);
        pd += __shfl_xor(pd, o, 32);
    }
    if ((t & 31) == 0) {
        dots[t >> 5] = ps;
        dots[4 + (t >> 5)] = pd;
    }
}

// ---------------- layer 1: online softmax, single pass ----------------
__global__ void k_layer1(const float* __restrict__ x, const int* __restrict__ rowp,
                         const int* __restrict__ col, const float* __restrict__ dots,
                         float* __restrict__ S, int N) {
    int gid = blockIdx.x * blockDim.x + threadIdx.x;
    int n = gid >> 4;               // 16 lanes per node
    int lane = threadIdx.x & 15;
    if (n >= N) return;
    int s = rowp[n];
    int deg = rowp[n + 1] - s;
    float xd = x[n];
    float ds0 = dots[0], ds1 = dots[1], ds2 = dots[2], ds3 = dots[3];
    float t0 = xd * dots[4], t1 = xd * dots[5], t2 = xd * dots[6], t3 = xd * dots[7];
    float m0 = NEGBIG, m1 = NEGBIG, m2 = NEGBIG, m3 = NEGBIG;
    float p0 = 0.f, p1 = 0.f, p2 = 0.f, p3 = 0.f;
    float q0 = 0.f, q1 = 0.f, q2 = 0.f, q3 = 0.f;
    for (int i = lane; i < deg; i += 16) {
        float xs = x[col[s + i]];
        float e0 = LRELU(fmaf(xs, ds0, t0));
        if (e0 > m0) { float r = __expf(m0 - e0); p0 *= r; q0 *= r; m0 = e0; }
        float w0 = __expf(e0 - m0); p0 += w0; q0 = fmaf(w0, xs, q0);
        float e1 = LRELU(fmaf(xs, ds1, t1));
        if (e1 > m1) { float r = __expf(m1 - e1); p1 *= r; q1 *= r; m1 = e1; }
        float w1 = __expf(e1 - m1); p1 += w1; q1 = fmaf(w1, xs, q1);
        float e2 = LRELU(fmaf(xs, ds2, t2));
        if (e2 > m2) { float r = __expf(m2 - e2); p2 *= r; q2 *= r; m2 = e2; }
        float w2 = __expf(e2 - m2); p2 += w2; q2 = fmaf(w2, xs, q2);
        float e3 = LRELU(fmaf(xs, ds3, t3));
        if (e3 > m3) { float r = __expf(m3 - e3); p3 *= r; q3 *= r; m3 = e3; }
        float w3 = __expf(e3 - m3); p3 += w3; q3 = fmaf(w3, xs, q3);
    }
    // cross-lane: global max per head, rescale, then sum
    float M0 = m0, M1 = m1, M2 = m2, M3 = m3;
    #pragma unroll
    for (int o = 8; o; o >>= 1) {
        M0 = fmaxf(M0, __shfl_xor(M0, o, 16));
        M1 = fmaxf(M1, __shfl_xor(M1, o, 16));
        M2 = fmaxf(M2, __shfl_xor(M2, o, 16));
        M3 = fmaxf(M3, __shfl_xor(M3, o, 16));
    }
    float r0 = __expf(m0 - M0), r1 = __expf(m1 - M1), r2 = __expf(m2 - M2), r3 = __expf(m3 - M3);
    p0 *= r0; q0 *= r0; p1 *= r1; q1 *= r1;
    p2 *= r2; q2 *= r2; p3 *= r3; q3 *= r3;
    #pragma unroll
    for (int o = 8; o; o >>= 1) {
        p0 += __shfl_xor(p0, o, 16); p1 += __shfl_xor(p1, o, 16);
        p2 += __shfl_xor(p2, o, 16); p3 += __shfl_xor(p3, o, 16);
        q0 += __shfl_xor(q0, o, 16); q1 += __shfl_xor(q1, o, 16);
        q2 += __shfl_xor(q2, o, 16); q3 += __shfl_xor(q3, o, 16);
    }
    if (lane == 0) {
        float4 r;
        r.x = q0 / (p0 + 1e-16f);
        r.y = q1 / (p1 + 1e-16f);
        r.z = q2 / (p2 + 1e-16f);
        r.w = q3 / (p3 + 1e-16f);
        *(float4*)(S + n * 4) = r;
    }
}

// ---------------- layer 2 node transform: h2 stored as bf16 rows (64 B) ----------------
__global__ void k_h2(const float* __restrict__ S, const float* __restrict__ W1,
                     const float* __restrict__ b1, const float* __restrict__ W2,
                     const float* __restrict__ a2s, const float* __restrict__ a2d,
                     unsigned short* __restrict__ h2b, float* __restrict__ es2,
                     float* __restrict__ ed2, int N) {
    __shared__ float sW2[4096];
    __shared__ float sW1[128];
    __shared__ float sb1[128];
    for (int i = threadIdx.x; i < 4096; i += blockDim.x) sW2[i] = W2[i];
    if (threadIdx.x < 128) {
        sW1[threadIdx.x] = W1[threadIdx.x];
        sb1[threadIdx.x] = b1[threadIdx.x];
    }
    __syncthreads();
    int n = blockIdx.x * blockDim.x + threadIdx.x;
    if (n >= N) return;
    float sv0 = S[n * 4 + 0], sv1 = S[n * 4 + 1], sv2 = S[n * 4 + 2], sv3 = S[n * 4 + 3];
    float acc[32];
    #pragma unroll
    for (int c = 0; c < 32; ++c) acc[c] = 0.f;
    #pragma unroll
    for (int h = 0; h < 4; ++h) {
        float sh = (h == 0) ? sv0 : (h == 1) ? sv1 : (h == 2) ? sv2 : sv3;
        for (int cc = 0; cc < 32; ++cc) {
            int hc = h * 32 + cc;
            float x1 = fmaf(sh, sW1[hc], sb1[hc]);
            x1 = x1 > 0.f ? x1 : 0.f;
            const float* w2row = &sW2[hc * 32];
            #pragma unroll
            for (int c = 0; c < 32; ++c) acc[c] = fmaf(x1, w2row[c], acc[c]);
        }
    }
    float es = 0.f, edv = 0.f;
    #pragma unroll
    for (int c = 0; c < 32; ++c) {
        es = fmaf(acc[c], a2s[c], es);
        edv = fmaf(acc[c], a2d[c], edv);
    }
    alignas(16) unsigned short hr[32];
    #pragma unroll
    for (int c = 0; c < 32; ++c) hr[c] = f2bf(acc[c]);
    uint4* dst = (uint4*)(h2b + (size_t)n * 32);
    const uint4* srcv = (const uint4*)hr;
    #pragma unroll
    for (int q = 0; q < 4; ++q) dst[q] = srcv[q];
    es2[n] = es;
    ed2[n] = edv;
}

// ---------------- layer 2 aggregation: online softmax, bf16 h2, 16 edge-slots x 4 cgs ----------------
__global__ void k_agg(const unsigned short* __restrict__ h2b, const float* __restrict__ es2,
                      const float* __restrict__ ed2, const int* __restrict__ rowp,
                      const int* __restrict__ col, const float* __restrict__ b2,
                      float* __restrict__ x2buf, int N) {
    int gid = blockIdx.x * blockDim.x + threadIdx.x;
    int n = gid >> 6;               // 64 lanes per node
    int lane = threadIdx.x & 63;
    if (n >= N) return;
    int s = rowp[n];
    int deg = rowp[n + 1] - s;
    float ed = ed2[n];
    int slot = lane >> 2;           // 16 edge slots
    int cg = lane & 3;              // 4 channel-groups of 8 channels
    float m = NEGBIG, sump = 0.f;
    float a0 = 0.f, a1 = 0.f, a2 = 0.f, a3 = 0.f, a4 = 0.f, a5 = 0.f, a6 = 0.f, a7 = 0.f;
    for (int j = slot; j < deg; j += 16) {
        int sidx = col[s + j];
        float e = LRELU(es2[sidx] + ed);
        if (e > m) {
            float r = __expf(m - e);
            sump *= r;
            a0 *= r; a1 *= r; a2 *= r; a3 *= r; a4 *= r; a5 *= r; a6 *= r; a7 *= r;
            m = e;
        }
        float p = __expf(e - m);
        sump += p;
        uint4 hv = *(const uint4*)(h2b + (size_t)sidx * 32 + cg * 8);
        a0 = fmaf(p, bfl(hv.x), a0); a1 = fmaf(p, bfh(hv.x), a1);
        a2 = fmaf(p, bfl(hv.y), a2); a3 = fmaf(p, bfh(hv.y), a3);
        a4 = fmaf(p, bfl(hv.z), a4); a5 = fmaf(p, bfh(hv.z), a5);
        a6 = fmaf(p, bfl(hv.w), a6); a7 = fmaf(p, bfh(hv.w), a7);
    }
    // cross-slot (lane bits 2..5): global max, rescale, sum
    float M = m;
    #pragma unroll
    for (int o = 4; o <= 32; o <<= 1) M = fmaxf(M, __shfl_xor(M, o, 64));
    float r = __expf(m - M);
    sump *= r;
    a0 *= r; a1 *= r; a2 *= r; a3 *= r; a4 *= r; a5 *= r; a6 *= r; a7 *= r;
    #pragma unroll
    for (int o = 4; o <= 32; o <<= 1) {
        sump += __shfl_xor(sump, o, 64);
        a0 += __shfl_xor(a0, o, 64); a1 += __shfl_xor(a1, o, 64);
        a2 += __shfl_xor(a2, o, 64); a3 += __shfl_xor(a3, o, 64);
        a4 += __shfl_xor(a4, o, 64); a5 += __shfl_xor(a5, o, 64);
        a6 += __shfl_xor(a6, o, 64); a7 += __shfl_xor(a7, o, 64);
    }
    if (slot == 0) {                // lanes 0..3, each owns channels 8cg..8cg+7
        float inv = 1.0f / (sump + 1e-16f);
        const float* bb = b2 + cg * 8;
        float v[8] = {a0, a1, a2, a3, a4, a5, a6, a7};
        float4 r0, r1;
        float* rp = &r0.x;
        #pragma unroll
        for (int q = 0; q < 4; ++q) {
            float t = fmaf(v[q], inv, bb[q]);
            rp[q] = t > 0.f ? t : 0.f;
        }
        float* rp1 = &r1.x;
        #pragma unroll
        for (int q = 0; q < 4; ++q) {
            float t = fmaf(v[4 + q], inv, bb[4 + q]);
            rp1[q] = t > 0.f ? t : 0.f;
        }
        float4* dst = (float4*)(x2buf + (size_t)n * 32 + cg * 8);
        dst[0] = r0;
        dst[1] = r1;
    }
}

// ---------------- pooling + head: one block per graph, no atomics ----------------
__global__ void k_pool(const float* __restrict__ x2buf, const int* __restrict__ batch,
                       const float* __restrict__ lin_w, const float* __restrict__ lin_b,
                       float* __restrict__ out, int N) {
    int g = blockIdx.x;
    __shared__ int sr[2];
    if (threadIdx.x == 0) {
        int lo = 0, hi = N;
        while (lo < hi) { int mid = (lo + hi) >> 1; if (batch[mid] < g) lo = mid + 1; else hi = mid; }
        sr[0] = lo;
        int l2 = lo, h2v = N;
        while (l2 < h2v) { int mid = (l2 + h2v) >> 1; if (batch[mid] < g + 1) l2 = mid + 1; else h2v = mid; }
        sr[1] = l2;
    }
    __syncthreads();
    int lo = sr[0], hi = sr[1];
    int ch = threadIdx.x & 31;
    int slot = threadIdx.x >> 5;
    float acc = 0.f;
    for (int n = lo + slot; n < hi; n += 8)
        acc += x2buf[(size_t)n * 32 + ch];
    __shared__ float red[256];
    red[threadIdx.x] = acc;
    __syncthreads();
    #pragma unroll
    for (int o = 128; o >= 32; o >>= 1) {
        if (threadIdx.x < o) red[threadIdx.x] += red[threadIdx.x + o];
        __syncthreads();
    }
    if (threadIdx.x < 32) {
        float c = fmaxf((float)(hi - lo), 1.0f);
        float v = red[threadIdx.x] / c * lin_w[threadIdx.x];
        #pragma unroll
        for (int o = 16; o; o >>= 1) v += __shfl_xor(v, o, 32);
        if (threadIdx.x == 0) out[g] = 1.0f / (1.0f + __expf(-(v + lin_b[0])));
    }
}

extern "C" void kernel_launch(void* const* d_in, const int* in_sizes, int n_in,
                              void* d_out, int out_size, void* d_ws, size_t ws_size,
                              hipStream_t stream) {
    const float* x     = (const float*)d_in[0];
    const int*   ei    = (const int*)d_in[1];
    const int*   batch = (const int*)d_in[2];
    const float* W1    = (const float*)d_in[4];
    const float* a1s   = (const float*)d_in[5];
    const float* a1d   = (const float*)d_in[6];
    const float* b1    = (const float*)d_in[7];
    const float* W2    = (const float*)d_in[8];
    const float* a2s   = (const float*)d_in[9];
    const float* a2d   = (const float*)d_in[10];
    const float* b2    = (const float*)d_in[11];
    const float* lin_w = (const float*)d_in[12];
    const float* lin_b = (const float*)d_in[13];
    float* out = (float*)d_out;

    int N = in_sizes[0];
    int E = in_sizes[1] / 2;
    int ET = E + N;
    int G = out_size;
    int nb = (N + 127) >> 7;        // dst-buckets of 128 nodes

    char* ws = (char*)d_ws;
    size_t off = 0;
    auto alloc = [&](size_t bytes) -> char* {
        char* p = ws + off;
        off = (off + bytes + 255) & ~(size_t)255;
        return p;
    };
    int*   bucket_cnt    = (int*)alloc(1024 * 4);
    int*   bucket_start  = (int*)alloc(1025 * 4);
    int*   bucket_cursor = (int*)alloc(1024 * 4);
    int*   pairbuf = (int*)alloc((size_t)ET * 4);
    int*   rowp    = (int*)alloc((size_t)(N + 1) * 4);
    int*   col     = (int*)alloc((size_t)ET * 4);
    float* S       = (float*)alloc((size_t)N * 16);
    unsigned short* h2b = (unsigned short*)alloc((size_t)N * 64);
    float* es2     = (float*)alloc((size_t)N * 4);
    float* ed2     = (float*)alloc((size_t)N * 4);
    float* dots    = (float*)alloc(32);
    float* x2buf   = (float*)alloc((size_t)N * 128);

    hipMemsetAsync(bucket_cnt, 0, (size_t)nb * 4, stream);

    int nblk = (ET + 8191) / 8192;
    k_cnt<<<nblk, 256, 0, stream>>>(ei, bucket_cnt, E, N, nb);
    k_scanB<<<1, 1024, 0, stream>>>(bucket_cnt, bucket_start, bucket_cursor, nb);
    k_scat<<<nblk, 256, 0, stream>>>(ei, bucket_cursor, pairbuf, E, N, nb);
    k_build<<<nb, 256, 0, stream>>>(pairbuf, bucket_start, rowp, col, N, nb);
    k_pre<<<1, 128, 0, stream>>>(W1, a1s, a1d, dots);
    k_layer1<<<(N + 15) / 16, 256, 0, stream>>>(x, rowp, col, dots, S, N);
    k_h2<<<(N + 255) / 256, 256, 0, stream>>>(S, W1, b1, W2, a2s, a2d, h2b, es2, ed2, N);
    k_agg<<<((size_t)N * 64 + 255) / 256, 256, 0, stream>>>(h2b, es2, ed2, rowp, col, b2, x2buf, N);
    k_pool<<<G, 256, 0, stream>>>(x2buf, batch, lin_w, lin_b, out, N);
}

// Round 6
// 182.788 us; speedup vs baseline: 7.8210x; 1.2339x over previous
//
#include <hip/hip_runtime.h>
#include <hip/hip_bf16.h>

#define LRELU(v) ((v) > 0.0f ? (v) : 0.2f * (v))
#define NEGBIG (-3.4e38f)
#define PPARTS 32

__device__ __forceinline__ unsigned short f2bf(float f) {
    unsigned int u = __float_as_uint(f);
    unsigned int r = (u >> 16) & 1;
    u += 0x7fff + r;                 // round-to-nearest-even
    return (unsigned short)(u >> 16);
}
__device__ __forceinline__ float bfl(unsigned int u) {  // low bf16 of a uint32
    return __uint_as_float(u << 16);
}
__device__ __forceinline__ float bfh(unsigned int u) {  // high bf16 of a uint32
    return __uint_as_float(u & 0xffff0000u);
}

// ================= CSR build via dst-bucket sort (128 dst-nodes per bucket) =================
__global__ void k_cnt(const int* __restrict__ ei, int* __restrict__ bucket_cnt,
                      int E, int N, int nb) {
    __shared__ int h[1024];
    for (int i = threadIdx.x; i < nb; i += 256) h[i] = 0;
    __syncthreads();
    int ET = E + N;
    int base = blockIdx.x * 8192;
    int end = base + 8192 < ET ? base + 8192 : ET;
    for (int e = base + threadIdx.x; e < end; e += 256) {
        int d = (e < E) ? ei[E + e] : (e - E);
        atomicAdd(&h[d >> 7], 1);
    }
    __syncthreads();
    for (int i = threadIdx.x; i < nb; i += 256)
        if (h[i]) atomicAdd(&bucket_cnt[i], h[i]);
}

__global__ void k_scanB(const int* __restrict__ bucket_cnt, int* __restrict__ bucket_start,
                        int* __restrict__ bucket_cursor, int nb) {
    __shared__ int wsum[16];
    int t = threadIdx.x;            // 1024 threads
    int v = (t < nb) ? bucket_cnt[t] : 0;
    int lane = t & 63, w = t >> 6;
    int sv = v;
    #pragma unroll
    for (int o = 1; o < 64; o <<= 1) {
        int u = __shfl_up(sv, o, 64);
        if (lane >= o) sv += u;
    }
    if (lane == 63) wsum[w] = sv;
    __syncthreads();
    if (t < 16) {
        int ws2 = wsum[t];
        #pragma unroll
        for (int o = 1; o < 16; o <<= 1) {
            int u = __shfl_up(ws2, o, 16);
            if (t >= o) ws2 += u;
        }
        wsum[t] = ws2;
    }
    __syncthreads();
    int excl = sv - v + (w ? wsum[w - 1] : 0);
    if (t < nb) { bucket_start[t] = excl; bucket_cursor[t] = excl; }
    if (t == nb - 1) bucket_start[nb] = excl + v;
}

__global__ void k_scat(const int* __restrict__ ei, int* __restrict__ bucket_cursor,
                       int* __restrict__ pairbuf, int E, int N, int nb) {
    __shared__ int h[1024];
    __shared__ int basearr[1024];
    for (int i = threadIdx.x; i < nb; i += 256) h[i] = 0;
    __syncthreads();
    int ET = E + N;
    int base = blockIdx.x * 8192;
    int end = base + 8192 < ET ? base + 8192 : ET;
    for (int e = base + threadIdx.x; e < end; e += 256) {
        int d = (e < E) ? ei[E + e] : (e - E);
        atomicAdd(&h[d >> 7], 1);
    }
    __syncthreads();
    for (int i = threadIdx.x; i < nb; i += 256) {
        int c = h[i];
        basearr[i] = c ? atomicAdd(&bucket_cursor[i], c) : 0;
        h[i] = 0;
    }
    __syncthreads();
    for (int e = base + threadIdx.x; e < end; e += 256) {
        int s, d;
        if (e < E) { s = ei[e]; d = ei[E + e]; } else { s = d = e - E; }
        int b = d >> 7;
        int pos = basearr[b] + atomicAdd(&h[b], 1);
        pairbuf[pos] = (s << 7) | (d & 127);
    }
}

__global__ void k_build(const int* __restrict__ pairbuf, const int* __restrict__ bucket_start,
                        int* __restrict__ rowp, int* __restrict__ col, int N, int nb) {
    int b = blockIdx.x;
    __shared__ int deg[128];
    __shared__ int inc[128];
    __shared__ int rbase[128];
    __shared__ int cur[128];
    int s0 = bucket_start[b], s1 = bucket_start[b + 1];
    if (threadIdx.x < 128) deg[threadIdx.x] = 0;
    __syncthreads();
    for (int i = s0 + threadIdx.x; i < s1; i += 256)
        atomicAdd(&deg[pairbuf[i] & 127], 1);
    __syncthreads();
    if (threadIdx.x < 128) {
        int lane = threadIdx.x & 63;
        int sv = deg[threadIdx.x];
        #pragma unroll
        for (int o = 1; o < 64; o <<= 1) {
            int u = __shfl_up(sv, o, 64);
            if (lane >= o) sv += u;
        }
        inc[threadIdx.x] = sv;
    }
    __syncthreads();
    if (threadIdx.x < 128) {
        int excl = inc[threadIdx.x] - deg[threadIdx.x] + ((threadIdx.x >= 64) ? inc[63] : 0);
        rbase[threadIdx.x] = s0 + excl;
        cur[threadIdx.x] = 0;
        int node = (b << 7) + threadIdx.x;
        if (node < N) rowp[node] = s0 + excl;
    }
    __syncthreads();
    for (int i = s0 + threadIdx.x; i < s1; i += 256) {
        int p = pairbuf[i];
        int off = p & 127;
        int pos = rbase[off] + atomicAdd(&cur[off], 1);
        col[pos] = p >> 7;
    }
    if (b == 0 && threadIdx.x == 0) rowp[N] = bucket_start[nb];
}

// ---------------- layer-1 constants ----------------
__global__ void k_pre(const float* __restrict__ W1, const float* __restrict__ a1s,
                      const float* __restrict__ a1d, float* __restrict__ dots) {
    int t = threadIdx.x;            // 128 threads
    float w = W1[t];
    float ps = w * a1s[t];
    float pd = w * a1d[t];
    #pragma unroll
    for (int o = 16; o; o >>= 1) {
        ps += __shfl_xor(ps, o, 32);
        pd += __shfl_xor(pd, o, 32);
    }
    if ((t & 31) == 0) {
        dots[t >> 5] = ps;
        dots[4 + (t >> 5)] = pd;
    }
}

// ---------------- layer 1: online softmax, single pass ----------------
__global__ void k_layer1(const float* __restrict__ x, const int* __restrict__ rowp,
                         const int* __restrict__ col, const float* __restrict__ dots,
                         float* __restrict__ S, int N) {
    int gid = blockIdx.x * blockDim.x + threadIdx.x;
    int n = gid >> 4;               // 16 lanes per node
    int lane = threadIdx.x & 15;
    if (n >= N) return;
    int s = rowp[n];
    int deg = rowp[n + 1] - s;
    float xd = x[n];
    float ds0 = dots[0], ds1 = dots[1], ds2 = dots[2], ds3 = dots[3];
    float t0 = xd * dots[4], t1 = xd * dots[5], t2 = xd * dots[6], t3 = xd * dots[7];
    float m0 = NEGBIG, m1 = NEGBIG, m2 = NEGBIG, m3 = NEGBIG;
    float p0 = 0.f, p1 = 0.f, p2 = 0.f, p3 = 0.f;
    float q0 = 0.f, q1 = 0.f, q2 = 0.f, q3 = 0.f;
    for (int i = lane; i < deg; i += 16) {
        float xs = x[col[s + i]];
        float e0 = LRELU(fmaf(xs, ds0, t0));
        if (e0 > m0) { float r = __expf(m0 - e0); p0 *= r; q0 *= r; m0 = e0; }
        float w0 = __expf(e0 - m0); p0 += w0; q0 = fmaf(w0, xs, q0);
        float e1 = LRELU(fmaf(xs, ds1, t1));
        if (e1 > m1) { float r = __expf(m1 - e1); p1 *= r; q1 *= r; m1 = e1; }
        float w1 = __expf(e1 - m1); p1 += w1; q1 = fmaf(w1, xs, q1);
        float e2 = LRELU(fmaf(xs, ds2, t2));
        if (e2 > m2) { float r = __expf(m2 - e2); p2 *= r; q2 *= r; m2 = e2; }
        float w2 = __expf(e2 - m2); p2 += w2; q2 = fmaf(w2, xs, q2);
        float e3 = LRELU(fmaf(xs, ds3, t3));
        if (e3 > m3) { float r = __expf(m3 - e3); p3 *= r; q3 *= r; m3 = e3; }
        float w3 = __expf(e3 - m3); p3 += w3; q3 = fmaf(w3, xs, q3);
    }
    float M0 = m0, M1 = m1, M2 = m2, M3 = m3;
    #pragma unroll
    for (int o = 8; o; o >>= 1) {
        M0 = fmaxf(M0, __shfl_xor(M0, o, 16));
        M1 = fmaxf(M1, __shfl_xor(M1, o, 16));
        M2 = fmaxf(M2, __shfl_xor(M2, o, 16));
        M3 = fmaxf(M3, __shfl_xor(M3, o, 16));
    }
    float r0 = __expf(m0 - M0), r1 = __expf(m1 - M1), r2 = __expf(m2 - M2), r3 = __expf(m3 - M3);
    p0 *= r0; q0 *= r0; p1 *= r1; q1 *= r1;
    p2 *= r2; q2 *= r2; p3 *= r3; q3 *= r3;
    #pragma unroll
    for (int o = 8; o; o >>= 1) {
        p0 += __shfl_xor(p0, o, 16); p1 += __shfl_xor(p1, o, 16);
        p2 += __shfl_xor(p2, o, 16); p3 += __shfl_xor(p3, o, 16);
        q0 += __shfl_xor(q0, o, 16); q1 += __shfl_xor(q1, o, 16);
        q2 += __shfl_xor(q2, o, 16); q3 += __shfl_xor(q3, o, 16);
    }
    if (lane == 0) {
        float4 r;
        r.x = q0 / (p0 + 1e-16f);
        r.y = q1 / (p1 + 1e-16f);
        r.z = q2 / (p2 + 1e-16f);
        r.w = q3 / (p3 + 1e-16f);
        *(float4*)(S + n * 4) = r;
    }
}

// ---------------- layer 2 node transform: h2 stored as bf16 rows (64 B) ----------------
__global__ void k_h2(const float* __restrict__ S, const float* __restrict__ W1,
                     const float* __restrict__ b1, const float* __restrict__ W2,
                     const float* __restrict__ a2s, const float* __restrict__ a2d,
                     unsigned short* __restrict__ h2b, float* __restrict__ es2,
                     float* __restrict__ ed2, int N) {
    __shared__ float sW2[4096];
    __shared__ float sW1[128];
    __shared__ float sb1[128];
    for (int i = threadIdx.x; i < 4096; i += blockDim.x) sW2[i] = W2[i];
    if (threadIdx.x < 128) {
        sW1[threadIdx.x] = W1[threadIdx.x];
        sb1[threadIdx.x] = b1[threadIdx.x];
    }
    __syncthreads();
    int n = blockIdx.x * blockDim.x + threadIdx.x;
    if (n >= N) return;
    float sv0 = S[n * 4 + 0], sv1 = S[n * 4 + 1], sv2 = S[n * 4 + 2], sv3 = S[n * 4 + 3];
    float acc[32];
    #pragma unroll
    for (int c = 0; c < 32; ++c) acc[c] = 0.f;
    #pragma unroll
    for (int h = 0; h < 4; ++h) {
        float sh = (h == 0) ? sv0 : (h == 1) ? sv1 : (h == 2) ? sv2 : sv3;
        for (int cc = 0; cc < 32; ++cc) {
            int hc = h * 32 + cc;
            float x1 = fmaf(sh, sW1[hc], sb1[hc]);
            x1 = x1 > 0.f ? x1 : 0.f;
            const float* w2row = &sW2[hc * 32];
            #pragma unroll
            for (int c = 0; c < 32; ++c) acc[c] = fmaf(x1, w2row[c], acc[c]);
        }
    }
    float es = 0.f, edv = 0.f;
    #pragma unroll
    for (int c = 0; c < 32; ++c) {
        es = fmaf(acc[c], a2s[c], es);
        edv = fmaf(acc[c], a2d[c], edv);
    }
    alignas(16) unsigned short hr[32];
    #pragma unroll
    for (int c = 0; c < 32; ++c) hr[c] = f2bf(acc[c]);
    uint4* dst = (uint4*)(h2b + (size_t)n * 32);
    const uint4* srcv = (const uint4*)hr;
    #pragma unroll
    for (int q = 0; q < 4; ++q) dst[q] = srcv[q];
    es2[n] = es;
    ed2[n] = edv;
}

// ---------------- layer 2 aggregation: online softmax, bf16 h2, 16 edge-slots x 4 cgs ----------------
__global__ void k_agg(const unsigned short* __restrict__ h2b, const float* __restrict__ es2,
                      const float* __restrict__ ed2, const int* __restrict__ rowp,
                      const int* __restrict__ col, const float* __restrict__ b2,
                      float* __restrict__ x2buf, int N) {
    int gid = blockIdx.x * blockDim.x + threadIdx.x;
    int n = gid >> 6;               // 64 lanes per node
    int lane = threadIdx.x & 63;
    if (n >= N) return;
    int s = rowp[n];
    int deg = rowp[n + 1] - s;
    float ed = ed2[n];
    int slot = lane >> 2;           // 16 edge slots
    int cg = lane & 3;              // 4 channel-groups of 8 channels
    float m = NEGBIG, sump = 0.f;
    float a0 = 0.f, a1 = 0.f, a2 = 0.f, a3 = 0.f, a4 = 0.f, a5 = 0.f, a6 = 0.f, a7 = 0.f;
    for (int j = slot; j < deg; j += 16) {
        int sidx = col[s + j];
        float e = LRELU(es2[sidx] + ed);
        if (e > m) {
            float r = __expf(m - e);
            sump *= r;
            a0 *= r; a1 *= r; a2 *= r; a3 *= r; a4 *= r; a5 *= r; a6 *= r; a7 *= r;
            m = e;
        }
        float p = __expf(e - m);
        sump += p;
        uint4 hv = *(const uint4*)(h2b + (size_t)sidx * 32 + cg * 8);
        a0 = fmaf(p, bfl(hv.x), a0); a1 = fmaf(p, bfh(hv.x), a1);
        a2 = fmaf(p, bfl(hv.y), a2); a3 = fmaf(p, bfh(hv.y), a3);
        a4 = fmaf(p, bfl(hv.z), a4); a5 = fmaf(p, bfh(hv.z), a5);
        a6 = fmaf(p, bfl(hv.w), a6); a7 = fmaf(p, bfh(hv.w), a7);
    }
    float M = m;
    #pragma unroll
    for (int o = 4; o <= 32; o <<= 1) M = fmaxf(M, __shfl_xor(M, o, 64));
    float r = __expf(m - M);
    sump *= r;
    a0 *= r; a1 *= r; a2 *= r; a3 *= r; a4 *= r; a5 *= r; a6 *= r; a7 *= r;
    #pragma unroll
    for (int o = 4; o <= 32; o <<= 1) {
        sump += __shfl_xor(sump, o, 64);
        a0 += __shfl_xor(a0, o, 64); a1 += __shfl_xor(a1, o, 64);
        a2 += __shfl_xor(a2, o, 64); a3 += __shfl_xor(a3, o, 64);
        a4 += __shfl_xor(a4, o, 64); a5 += __shfl_xor(a5, o, 64);
        a6 += __shfl_xor(a6, o, 64); a7 += __shfl_xor(a7, o, 64);
    }
    if (slot == 0) {                // lanes 0..3, each owns channels 8cg..8cg+7
        float inv = 1.0f / (sump + 1e-16f);
        const float* bb = b2 + cg * 8;
        float v[8] = {a0, a1, a2, a3, a4, a5, a6, a7};
        float4 r0, r1;
        float* rp = &r0.x;
        #pragma unroll
        for (int q = 0; q < 4; ++q) {
            float t = fmaf(v[q], inv, bb[q]);
            rp[q] = t > 0.f ? t : 0.f;
        }
        float* rp1 = &r1.x;
        #pragma unroll
        for (int q = 0; q < 4; ++q) {
            float t = fmaf(v[4 + q], inv, bb[4 + q]);
            rp1[q] = t > 0.f ? t : 0.f;
        }
        float4* dst = (float4*)(x2buf + (size_t)n * 32 + cg * 8);
        dst[0] = r0;
        dst[1] = r1;
    }
}

// ---------------- pooling stage 1: G*PPARTS blocks, no atomics ----------------
__global__ void k_psum(const float* __restrict__ x2buf, const int* __restrict__ batch,
                       float* __restrict__ partial, int N) {
    int g = blockIdx.x / PPARTS;
    int part = blockIdx.x % PPARTS;
    __shared__ int sr[2];
    if (threadIdx.x == 0) {
        int lo = 0, hi = N;
        while (lo < hi) { int mid = (lo + hi) >> 1; if (batch[mid] < g) lo = mid + 1; else hi = mid; }
        sr[0] = lo;
        int l2 = lo, h2v = N;
        while (l2 < h2v) { int mid = (l2 + h2v) >> 1; if (batch[mid] < g + 1) l2 = mid + 1; else h2v = mid; }
        sr[1] = l2;
    }
    __syncthreads();
    int lo = sr[0], hi = sr[1];
    int cs = (hi - lo + PPARTS - 1) / PPARTS;
    int start = lo + part * cs;
    int end = start + cs < hi ? start + cs : hi;
    int ch = threadIdx.x & 31;
    int slot = threadIdx.x >> 5;    // 8 node slots
    float acc = 0.f;
    for (int n = start + slot; n < end; n += 8)
        acc += x2buf[(size_t)n * 32 + ch];
    __shared__ float red[256];
    red[threadIdx.x] = acc;
    __syncthreads();
    #pragma unroll
    for (int o = 128; o >= 32; o >>= 1) {
        if (threadIdx.x < o) red[threadIdx.x] += red[threadIdx.x + o];
        __syncthreads();
    }
    if (threadIdx.x < 32)
        partial[(size_t)(g * PPARTS + part) * 32 + threadIdx.x] = red[threadIdx.x];
}

// ---------------- pooling stage 2 + head: one block per graph ----------------
__global__ void k_head(const float* __restrict__ partial, const int* __restrict__ batch,
                       const float* __restrict__ lin_w, const float* __restrict__ lin_b,
                       float* __restrict__ out, int N) {
    int g = blockIdx.x;
    int t = threadIdx.x;            // 64 threads
    int ch = t & 31;
    int half = t >> 5;
    float acc = 0.f;
    for (int p = half * (PPARTS / 2); p < (half + 1) * (PPARTS / 2); ++p)
        acc += partial[(size_t)(g * PPARTS + p) * 32 + ch];
    acc += __shfl_xor(acc, 32, 64);
    // node count via binary search (all lanes redundantly)
    int lo = 0, hi = N;
    while (lo < hi) { int mid = (lo + hi) >> 1; if (batch[mid] < g) lo = mid + 1; else hi = mid; }
    int l2 = lo, h2v = N;
    while (l2 < h2v) { int mid = (l2 + h2v) >> 1; if (batch[mid] < g + 1) l2 = mid + 1; else h2v = mid; }
    float c = fmaxf((float)(h2v - lo), 1.0f);
    float v = acc / c * lin_w[ch];
    #pragma unroll
    for (int o = 16; o; o >>= 1) v += __shfl_xor(v, o, 32);
    if (t == 0) out[g] = 1.0f / (1.0f + __expf(-(v + lin_b[0])));
}

extern "C" void kernel_launch(void* const* d_in, const int* in_sizes, int n_in,
                              void* d_out, int out_size, void* d_ws, size_t ws_size,
                              hipStream_t stream) {
    const float* x     = (const float*)d_in[0];
    const int*   ei    = (const int*)d_in[1];
    const int*   batch = (const int*)d_in[2];
    const float* W1    = (const float*)d_in[4];
    const float* a1s   = (const float*)d_in[5];
    const float* a1d   = (const float*)d_in[6];
    const float* b1    = (const float*)d_in[7];
    const float* W2    = (const float*)d_in[8];
    const float* a2s   = (const float*)d_in[9];
    const float* a2d   = (const float*)d_in[10];
    const float* b2    = (const float*)d_in[11];
    const float* lin_w = (const float*)d_in[12];
    const float* lin_b = (const float*)d_in[13];
    float* out = (float*)d_out;

    int N = in_sizes[0];
    int E = in_sizes[1] / 2;
    int ET = E + N;
    int G = out_size;
    int nb = (N + 127) >> 7;        // dst-buckets of 128 nodes

    char* ws = (char*)d_ws;
    size_t off = 0;
    auto alloc = [&](size_t bytes) -> char* {
        char* p = ws + off;
        off = (off + bytes + 255) & ~(size_t)255;
        return p;
    };
    int*   bucket_cnt    = (int*)alloc(1024 * 4);
    int*   bucket_start  = (int*)alloc(1025 * 4);
    int*   bucket_cursor = (int*)alloc(1024 * 4);
    int*   pairbuf = (int*)alloc((size_t)ET * 4);
    int*   rowp    = (int*)alloc((size_t)(N + 1) * 4);
    int*   col     = (int*)alloc((size_t)ET * 4);
    float* S       = (float*)alloc((size_t)N * 16);
    unsigned short* h2b = (unsigned short*)alloc((size_t)N * 64);
    float* es2     = (float*)alloc((size_t)N * 4);
    float* ed2     = (float*)alloc((size_t)N * 4);
    float* dots    = (float*)alloc(32);
    float* x2buf   = (float*)alloc((size_t)N * 128);
    float* partial = (float*)alloc((size_t)G * PPARTS * 32 * 4);

    hipMemsetAsync(bucket_cnt, 0, (size_t)nb * 4, stream);

    int nblk = (ET + 8191) / 8192;
    k_cnt<<<nblk, 256, 0, stream>>>(ei, bucket_cnt, E, N, nb);
    k_scanB<<<1, 1024, 0, stream>>>(bucket_cnt, bucket_start, bucket_cursor, nb);
    k_scat<<<nblk, 256, 0, stream>>>(ei, bucket_cursor, pairbuf, E, N, nb);
    k_build<<<nb, 256, 0, stream>>>(pairbuf, bucket_start, rowp, col, N, nb);
    k_pre<<<1, 128, 0, stream>>>(W1, a1s, a1d, dots);
    k_layer1<<<(N + 15) / 16, 256, 0, stream>>>(x, rowp, col, dots, S, N);
    k_h2<<<(N + 255) / 256, 256, 0, stream>>>(S, W1, b1, W2, a2s, a2d, h2b, es2, ed2, N);
    k_agg<<<((size_t)N * 64 + 255) / 256, 256, 0, stream>>>(h2b, es2, ed2, rowp, col, b2, x2buf, N);
    k_psum<<<G * PPARTS, 256, 0, stream>>>(x2buf, batch, partial, N);
    k_head<<<G, 64, 0, stream>>>(partial, batch, lin_w, lin_b, out, N);
}

// Round 7
// 169.507 us; speedup vs baseline: 8.4338x; 1.0784x over previous
//
#include <hip/hip_runtime.h>
#include <hip/hip_bf16.h>

#define LRELU(v) ((v) > 0.0f ? (v) : 0.2f * (v))
#define PPARTS 32

__device__ __forceinline__ unsigned short f2bf(float f) {
    unsigned int u = __float_as_uint(f);
    unsigned int r = (u >> 16) & 1;
    u += 0x7fff + r;                 // round-to-nearest-even
    return (unsigned short)(u >> 16);
}
__device__ __forceinline__ float bfl(unsigned int u) {  // low bf16 of a uint32
    return __uint_as_float(u << 16);
}
__device__ __forceinline__ float bfh(unsigned int u) {  // high bf16 of a uint32
    return __uint_as_float(u & 0xffff0000u);
}

// ================= CSR build via dst-bucket sort (128 dst-nodes per bucket) =================
// Pass 1: per-block LDS histogram -> global bucket counts + persisted per-block histogram
__global__ void k_cnt(const int* __restrict__ ei, int* __restrict__ bucket_cnt,
                      int* __restrict__ blockhist, int E, int N, int nb) {
    __shared__ int h[1024];
    for (int i = threadIdx.x; i < nb; i += 256) h[i] = 0;
    __syncthreads();
    int ET = E + N;
    int base = blockIdx.x * 8192;
    int end = base + 8192 < ET ? base + 8192 : ET;
    for (int e = base + threadIdx.x; e < end; e += 256) {
        int d = (e < E) ? ei[E + e] : (e - E);
        atomicAdd(&h[d >> 7], 1);
    }
    __syncthreads();
    for (int i = threadIdx.x; i < nb; i += 256) {
        int c = h[i];
        if (c) atomicAdd(&bucket_cnt[i], c);
        blockhist[(size_t)blockIdx.x * 1024 + i] = c;
    }
}

// Pass 2: scan bucket counts (nb <= 1024); also computes layer-1 dot constants (was k_pre)
__global__ void k_scanB(const int* __restrict__ bucket_cnt, int* __restrict__ bucket_start,
                        int* __restrict__ bucket_cursor, int nb,
                        const float* __restrict__ W1, const float* __restrict__ a1s,
                        const float* __restrict__ a1d, float* __restrict__ dots) {
    int t = threadIdx.x;            // 1024 threads
    if (t < 128) {                  // fused k_pre
        float w = W1[t];
        float ps = w * a1s[t];
        float pd = w * a1d[t];
        #pragma unroll
        for (int o = 16; o; o >>= 1) {
            ps += __shfl_xor(ps, o, 32);
            pd += __shfl_xor(pd, o, 32);
        }
        if ((t & 31) == 0) {
            dots[t >> 5] = ps;
            dots[4 + (t >> 5)] = pd;
        }
    }
    __shared__ int wsum[16];
    int v = (t < nb) ? bucket_cnt[t] : 0;
    int lane = t & 63, w = t >> 6;
    int sv = v;
    #pragma unroll
    for (int o = 1; o < 64; o <<= 1) {
        int u = __shfl_up(sv, o, 64);
        if (lane >= o) sv += u;
    }
    if (lane == 63) wsum[w] = sv;
    __syncthreads();
    if (t < 16) {
        int ws2 = wsum[t];
        #pragma unroll
        for (int o = 1; o < 16; o <<= 1) {
            int u = __shfl_up(ws2, o, 16);
            if (t >= o) ws2 += u;
        }
        wsum[t] = ws2;
    }
    __syncthreads();
    int excl = sv - v + (w ? wsum[w - 1] : 0);
    if (t < nb) { bucket_start[t] = excl; bucket_cursor[t] = excl; }
    if (t == nb - 1) bucket_start[nb] = excl + v;
}

// Pass 3: reserve ranges per bucket from persisted histogram, append packed (src<<7 | dstlocal)
__global__ void k_scat(const int* __restrict__ ei, const int* __restrict__ blockhist,
                       int* __restrict__ bucket_cursor, int* __restrict__ pairbuf,
                       int E, int N, int nb) {
    __shared__ int h[1024];
    __shared__ int basearr[1024];
    for (int i = threadIdx.x; i < nb; i += 256) {
        int c = blockhist[(size_t)blockIdx.x * 1024 + i];
        basearr[i] = c ? atomicAdd(&bucket_cursor[i], c) : 0;
        h[i] = 0;
    }
    __syncthreads();
    int ET = E + N;
    int base = blockIdx.x * 8192;
    int end = base + 8192 < ET ? base + 8192 : ET;
    for (int e = base + threadIdx.x; e < end; e += 256) {
        int s, d;
        if (e < E) { s = ei[e]; d = ei[E + e]; } else { s = d = e - E; }
        int b = d >> 7;
        int pos = basearr[b] + atomicAdd(&h[b], 1);
        pairbuf[pos] = (s << 7) | (d & 127);
    }
}

// Pass 4: one block per bucket -> rowp + col (all scatters inside an L1-resident window)
__global__ void k_build(const int* __restrict__ pairbuf, const int* __restrict__ bucket_start,
                        int* __restrict__ rowp, int* __restrict__ col, int N, int nb) {
    int b = blockIdx.x;
    __shared__ int deg[128];
    __shared__ int inc[128];
    __shared__ int rbase[128];
    __shared__ int cur[128];
    int s0 = bucket_start[b], s1 = bucket_start[b + 1];
    if (threadIdx.x < 128) deg[threadIdx.x] = 0;
    __syncthreads();
    for (int i = s0 + threadIdx.x; i < s1; i += 256)
        atomicAdd(&deg[pairbuf[i] & 127], 1);
    __syncthreads();
    if (threadIdx.x < 128) {
        int lane = threadIdx.x & 63;
        int sv = deg[threadIdx.x];
        #pragma unroll
        for (int o = 1; o < 64; o <<= 1) {
            int u = __shfl_up(sv, o, 64);
            if (lane >= o) sv += u;
        }
        inc[threadIdx.x] = sv;
    }
    __syncthreads();
    if (threadIdx.x < 128) {
        int excl = inc[threadIdx.x] - deg[threadIdx.x] + ((threadIdx.x >= 64) ? inc[63] : 0);
        rbase[threadIdx.x] = s0 + excl;
        cur[threadIdx.x] = 0;
        int node = (b << 7) + threadIdx.x;
        if (node < N) rowp[node] = s0 + excl;
    }
    __syncthreads();
    for (int i = s0 + threadIdx.x; i < s1; i += 256) {
        int p = pairbuf[i];
        int off = p & 127;
        int pos = rbase[off] + atomicAdd(&cur[off], 1);
        col[pos] = p >> 7;
    }
    if (b == 0 && threadIdx.x == 0) rowp[N] = bucket_start[nb];
}

// ---------------- layer 1: branch-free softmax (no max shift; |logit| <= ~1) ----------------
__global__ void k_layer1(const float* __restrict__ x, const int* __restrict__ rowp,
                         const int* __restrict__ col, const float* __restrict__ dots,
                         float* __restrict__ S, int N) {
    int gid = blockIdx.x * blockDim.x + threadIdx.x;
    int n = gid >> 4;               // 16 lanes per node
    int lane = threadIdx.x & 15;
    if (n >= N) return;
    int s = rowp[n];
    int deg = rowp[n + 1] - s;
    float xd = x[n];
    float ds0 = dots[0], ds1 = dots[1], ds2 = dots[2], ds3 = dots[3];
    float t0 = xd * dots[4], t1 = xd * dots[5], t2 = xd * dots[6], t3 = xd * dots[7];
    float p0 = 0.f, p1 = 0.f, p2 = 0.f, p3 = 0.f;
    float q0 = 0.f, q1 = 0.f, q2 = 0.f, q3 = 0.f;
    for (int i = lane; i < deg; i += 16) {
        float xs = x[col[s + i]];
        float e0 = LRELU(fmaf(xs, ds0, t0)); float w0 = __expf(e0); p0 += w0; q0 = fmaf(w0, xs, q0);
        float e1 = LRELU(fmaf(xs, ds1, t1)); float w1 = __expf(e1); p1 += w1; q1 = fmaf(w1, xs, q1);
        float e2 = LRELU(fmaf(xs, ds2, t2)); float w2 = __expf(e2); p2 += w2; q2 = fmaf(w2, xs, q2);
        float e3 = LRELU(fmaf(xs, ds3, t3)); float w3 = __expf(e3); p3 += w3; q3 = fmaf(w3, xs, q3);
    }
    #pragma unroll
    for (int o = 8; o; o >>= 1) {
        p0 += __shfl_xor(p0, o, 16); p1 += __shfl_xor(p1, o, 16);
        p2 += __shfl_xor(p2, o, 16); p3 += __shfl_xor(p3, o, 16);
        q0 += __shfl_xor(q0, o, 16); q1 += __shfl_xor(q1, o, 16);
        q2 += __shfl_xor(q2, o, 16); q3 += __shfl_xor(q3, o, 16);
    }
    if (lane == 0) {
        float4 r;
        r.x = q0 / (p0 + 1e-16f);
        r.y = q1 / (p1 + 1e-16f);
        r.z = q2 / (p2 + 1e-16f);
        r.w = q3 / (p3 + 1e-16f);
        *(float4*)(S + n * 4) = r;
    }
}

// ---------------- layer 2 node transform: h2 stored as bf16 rows (64 B) ----------------
__global__ void k_h2(const float* __restrict__ S, const float* __restrict__ W1,
                     const float* __restrict__ b1, const float* __restrict__ W2,
                     const float* __restrict__ a2s, const float* __restrict__ a2d,
                     unsigned short* __restrict__ h2b, float* __restrict__ es2,
                     float* __restrict__ ed2, int N) {
    __shared__ float sW2[4096];
    __shared__ float sW1[128];
    __shared__ float sb1[128];
    for (int i = threadIdx.x; i < 4096; i += blockDim.x) sW2[i] = W2[i];
    if (threadIdx.x < 128) {
        sW1[threadIdx.x] = W1[threadIdx.x];
        sb1[threadIdx.x] = b1[threadIdx.x];
    }
    __syncthreads();
    int n = blockIdx.x * blockDim.x + threadIdx.x;
    if (n >= N) return;
    float sv0 = S[n * 4 + 0], sv1 = S[n * 4 + 1], sv2 = S[n * 4 + 2], sv3 = S[n * 4 + 3];
    float acc[32];
    #pragma unroll
    for (int c = 0; c < 32; ++c) acc[c] = 0.f;
    #pragma unroll
    for (int h = 0; h < 4; ++h) {
        float sh = (h == 0) ? sv0 : (h == 1) ? sv1 : (h == 2) ? sv2 : sv3;
        for (int cc = 0; cc < 32; ++cc) {
            int hc = h * 32 + cc;
            float x1 = fmaf(sh, sW1[hc], sb1[hc]);
            x1 = x1 > 0.f ? x1 : 0.f;
            const float* w2row = &sW2[hc * 32];
            #pragma unroll
            for (int c = 0; c < 32; ++c) acc[c] = fmaf(x1, w2row[c], acc[c]);
        }
    }
    float es = 0.f, edv = 0.f;
    #pragma unroll
    for (int c = 0; c < 32; ++c) {
        es = fmaf(acc[c], a2s[c], es);
        edv = fmaf(acc[c], a2d[c], edv);
    }
    alignas(16) unsigned short hr[32];
    #pragma unroll
    for (int c = 0; c < 32; ++c) hr[c] = f2bf(acc[c]);
    uint4* dst = (uint4*)(h2b + (size_t)n * 32);
    const uint4* srcv = (const uint4*)hr;
    #pragma unroll
    for (int q = 0; q < 4; ++q) dst[q] = srcv[q];
    es2[n] = es;
    ed2[n] = edv;
}

// ---------------- layer 2 aggregation: branch-free softmax (|logit| <= ~10), bf16 h2 ----------------
__global__ void k_agg(const unsigned short* __restrict__ h2b, const float* __restrict__ es2,
                      const float* __restrict__ ed2, const int* __restrict__ rowp,
                      const int* __restrict__ col, const float* __restrict__ b2,
                      float* __restrict__ x2buf, int N) {
    int gid = blockIdx.x * blockDim.x + threadIdx.x;
    int n = gid >> 6;               // 64 lanes per node
    int lane = threadIdx.x & 63;
    if (n >= N) return;
    int s = rowp[n];
    int deg = rowp[n + 1] - s;
    float ed = ed2[n];
    int slot = lane >> 2;           // 16 edge slots
    int cg = lane & 3;              // 4 channel-groups of 8 channels
    float sump = 0.f;
    float a0 = 0.f, a1 = 0.f, a2 = 0.f, a3 = 0.f, a4 = 0.f, a5 = 0.f, a6 = 0.f, a7 = 0.f;
    for (int j = slot; j < deg; j += 16) {
        int sidx = col[s + j];
        float e = LRELU(es2[sidx] + ed);
        float p = __expf(e);
        sump += p;
        uint4 hv = *(const uint4*)(h2b + (size_t)sidx * 32 + cg * 8);
        a0 = fmaf(p, bfl(hv.x), a0); a1 = fmaf(p, bfh(hv.x), a1);
        a2 = fmaf(p, bfl(hv.y), a2); a3 = fmaf(p, bfh(hv.y), a3);
        a4 = fmaf(p, bfl(hv.z), a4); a5 = fmaf(p, bfh(hv.z), a5);
        a6 = fmaf(p, bfl(hv.w), a6); a7 = fmaf(p, bfh(hv.w), a7);
    }
    #pragma unroll
    for (int o = 4; o <= 32; o <<= 1) {
        sump += __shfl_xor(sump, o, 64);
        a0 += __shfl_xor(a0, o, 64); a1 += __shfl_xor(a1, o, 64);
        a2 += __shfl_xor(a2, o, 64); a3 += __shfl_xor(a3, o, 64);
        a4 += __shfl_xor(a4, o, 64); a5 += __shfl_xor(a5, o, 64);
        a6 += __shfl_xor(a6, o, 64); a7 += __shfl_xor(a7, o, 64);
    }
    if (slot == 0) {                // lanes 0..3, each owns channels 8cg..8cg+7
        float inv = 1.0f / (sump + 1e-16f);
        const float* bb = b2 + cg * 8;
        float v[8] = {a0, a1, a2, a3, a4, a5, a6, a7};
        float4 r0, r1;
        float* rp = &r0.x;
        #pragma unroll
        for (int q = 0; q < 4; ++q) {
            float t = fmaf(v[q], inv, bb[q]);
            rp[q] = t > 0.f ? t : 0.f;
        }
        float* rp1 = &r1.x;
        #pragma unroll
        for (int q = 0; q < 4; ++q) {
            float t = fmaf(v[4 + q], inv, bb[4 + q]);
            rp1[q] = t > 0.f ? t : 0.f;
        }
        float4* dst = (float4*)(x2buf + (size_t)n * 32 + cg * 8);
        dst[0] = r0;
        dst[1] = r1;
    }
}

// ---------------- pooling stage 1: G*PPARTS blocks, no atomics ----------------
__global__ void k_psum(const float* __restrict__ x2buf, const int* __restrict__ batch,
                       float* __restrict__ partial, int N) {
    int g = blockIdx.x / PPARTS;
    int part = blockIdx.x % PPARTS;
    __shared__ int sr[2];
    if (threadIdx.x == 0) {
        int lo = 0, hi = N;
        while (lo < hi) { int mid = (lo + hi) >> 1; if (batch[mid] < g) lo = mid + 1; else hi = mid; }
        sr[0] = lo;
        int l2 = lo, h2v = N;
        while (l2 < h2v) { int mid = (l2 + h2v) >> 1; if (batch[mid] < g + 1) l2 = mid + 1; else h2v = mid; }
        sr[1] = l2;
    }
    __syncthreads();
    int lo = sr[0], hi = sr[1];
    int cs = (hi - lo + PPARTS - 1) / PPARTS;
    int start = lo + part * cs;
    int end = start + cs < hi ? start + cs : hi;
    int ch = threadIdx.x & 31;
    int slot = threadIdx.x >> 5;    // 8 node slots
    float acc = 0.f;
    for (int n = start + slot; n < end; n += 8)
        acc += x2buf[(size_t)n * 32 + ch];
    __shared__ float red[256];
    red[threadIdx.x] = acc;
    __syncthreads();
    #pragma unroll
    for (int o = 128; o >= 32; o >>= 1) {
        if (threadIdx.x < o) red[threadIdx.x] += red[threadIdx.x + o];
        __syncthreads();
    }
    if (threadIdx.x < 32)
        partial[(size_t)(g * PPARTS + part) * 32 + threadIdx.x] = red[threadIdx.x];
}

// ---------------- pooling stage 2 + head: one block per graph ----------------
__global__ void k_head(const float* __restrict__ partial, const int* __restrict__ batch,
                       const float* __restrict__ lin_w, const float* __restrict__ lin_b,
                       float* __restrict__ out, int N) {
    int g = blockIdx.x;
    int t = threadIdx.x;            // 64 threads
    int ch = t & 31;
    int half = t >> 5;
    float acc = 0.f;
    for (int p = half * (PPARTS / 2); p < (half + 1) * (PPARTS / 2); ++p)
        acc += partial[(size_t)(g * PPARTS + p) * 32 + ch];
    acc += __shfl_xor(acc, 32, 64);
    int lo = 0, hi = N;
    while (lo < hi) { int mid = (lo + hi) >> 1; if (batch[mid] < g) lo = mid + 1; else hi = mid; }
    int l2 = lo, h2v = N;
    while (l2 < h2v) { int mid = (l2 + h2v) >> 1; if (batch[mid] < g + 1) l2 = mid + 1; else h2v = mid; }
    float c = fmaxf((float)(h2v - lo), 1.0f);
    float v = acc / c * lin_w[ch];
    #pragma unroll
    for (int o = 16; o; o >>= 1) v += __shfl_xor(v, o, 32);
    if (t == 0) out[g] = 1.0f / (1.0f + __expf(-(v + lin_b[0])));
}

extern "C" void kernel_launch(void* const* d_in, const int* in_sizes, int n_in,
                              void* d_out, int out_size, void* d_ws, size_t ws_size,
                              hipStream_t stream) {
    const float* x     = (const float*)d_in[0];
    const int*   ei    = (const int*)d_in[1];
    const int*   batch = (const int*)d_in[2];
    const float* W1    = (const float*)d_in[4];
    const float* a1s   = (const float*)d_in[5];
    const float* a1d   = (const float*)d_in[6];
    const float* b1    = (const float*)d_in[7];
    const float* W2    = (const float*)d_in[8];
    const float* a2s   = (const float*)d_in[9];
    const float* a2d   = (const float*)d_in[10];
    const float* b2    = (const float*)d_in[11];
    const float* lin_w = (const float*)d_in[12];
    const float* lin_b = (const float*)d_in[13];
    float* out = (float*)d_out;

    int N = in_sizes[0];
    int E = in_sizes[1] / 2;
    int ET = E + N;
    int G = out_size;
    int nb = (N + 127) >> 7;        // dst-buckets of 128 nodes
    int nblk = (ET + 8191) / 8192;

    char* ws = (char*)d_ws;
    size_t off = 0;
    auto alloc = [&](size_t bytes) -> char* {
        char* p = ws + off;
        off = (off + bytes + 255) & ~(size_t)255;
        return p;
    };
    int*   bucket_cnt    = (int*)alloc(1024 * 4);
    int*   bucket_start  = (int*)alloc(1025 * 4);
    int*   bucket_cursor = (int*)alloc(1024 * 4);
    int*   blockhist     = (int*)alloc((size_t)nblk * 1024 * 4);
    int*   pairbuf = (int*)alloc((size_t)ET * 4);
    int*   rowp    = (int*)alloc((size_t)(N + 1) * 4);
    int*   col     = (int*)alloc((size_t)ET * 4);
    float* S       = (float*)alloc((size_t)N * 16);
    unsigned short* h2b = (unsigned short*)alloc((size_t)N * 64);
    float* es2     = (float*)alloc((size_t)N * 4);
    float* ed2     = (float*)alloc((size_t)N * 4);
    float* dots    = (float*)alloc(32);
    float* x2buf   = (float*)alloc((size_t)N * 128);
    float* partial = (float*)alloc((size_t)G * PPARTS * 32 * 4);

    hipMemsetAsync(bucket_cnt, 0, (size_t)nb * 4, stream);

    k_cnt<<<nblk, 256, 0, stream>>>(ei, bucket_cnt, blockhist, E, N, nb);
    k_scanB<<<1, 1024, 0, stream>>>(bucket_cnt, bucket_start, bucket_cursor, nb, W1, a1s, a1d, dots);
    k_scat<<<nblk, 256, 0, stream>>>(ei, blockhist, bucket_cursor, pairbuf, E, N, nb);
    k_build<<<nb, 256, 0, stream>>>(pairbuf, bucket_start, rowp, col, N, nb);
    k_layer1<<<(N + 15) / 16, 256, 0, stream>>>(x, rowp, col, dots, S, N);
    k_h2<<<(N + 255) / 256, 256, 0, stream>>>(S, W1, b1, W2, a2s, a2d, h2b, es2, ed2, N);
    k_agg<<<((size_t)N * 64 + 255) / 256, 256, 0, stream>>>(h2b, es2, ed2, rowp, col, b2, x2buf, N);
    k_psum<<<G * PPARTS, 256, 0, stream>>>(x2buf, batch, partial, N);
    k_head<<<G, 64, 0, stream>>>(partial, batch, lin_w, lin_b, out, N);
}

// Round 8
// 167.239 us; speedup vs baseline: 8.5481x; 1.0136x over previous
//
#include <hip/hip_runtime.h>
#include <hip/hip_bf16.h>

#define LRELU(v) ((v) > 0.0f ? (v) : 0.2f * (v))
#define PPARTS 32

typedef float f32x2 __attribute__((ext_vector_type(2)));

__device__ __forceinline__ unsigned short f2bf(float f) {
    unsigned int u = __float_as_uint(f);
    unsigned int r = (u >> 16) & 1;
    u += 0x7fff + r;                 // round-to-nearest-even
    return (unsigned short)(u >> 16);
}
__device__ __forceinline__ float bf2f(unsigned short s) {
    return __uint_as_float(((unsigned int)s) << 16);
}

// ================= CSR build via dst-bucket sort (128 dst-nodes per bucket) =================
__global__ void k_cnt(const int* __restrict__ ei, int* __restrict__ bucket_cnt,
                      int* __restrict__ blockhist, int E, int N, int nb) {
    __shared__ int h[1024];
    for (int i = threadIdx.x; i < nb; i += 256) h[i] = 0;
    __syncthreads();
    int ET = E + N;
    int base = blockIdx.x * 8192;
    int end = base + 8192 < ET ? base + 8192 : ET;
    for (int e = base + threadIdx.x; e < end; e += 256) {
        int d = (e < E) ? ei[E + e] : (e - E);
        atomicAdd(&h[d >> 7], 1);
    }
    __syncthreads();
    for (int i = threadIdx.x; i < nb; i += 256) {
        int c = h[i];
        if (c) atomicAdd(&bucket_cnt[i], c);
        blockhist[(size_t)blockIdx.x * 1024 + i] = c;
    }
}

__global__ void k_scanB(const int* __restrict__ bucket_cnt, int* __restrict__ bucket_start,
                        int* __restrict__ bucket_cursor, int nb,
                        const float* __restrict__ W1, const float* __restrict__ a1s,
                        const float* __restrict__ a1d, float* __restrict__ dots) {
    int t = threadIdx.x;            // 1024 threads
    if (t < 128) {                  // fused k_pre
        float w = W1[t];
        float ps = w * a1s[t];
        float pd = w * a1d[t];
        #pragma unroll
        for (int o = 16; o; o >>= 1) {
            ps += __shfl_xor(ps, o, 32);
            pd += __shfl_xor(pd, o, 32);
        }
        if ((t & 31) == 0) {
            dots[t >> 5] = ps;
            dots[4 + (t >> 5)] = pd;
        }
    }
    __shared__ int wsum[16];
    int v = (t < nb) ? bucket_cnt[t] : 0;
    int lane = t & 63, w = t >> 6;
    int sv = v;
    #pragma unroll
    for (int o = 1; o < 64; o <<= 1) {
        int u = __shfl_up(sv, o, 64);
        if (lane >= o) sv += u;
    }
    if (lane == 63) wsum[w] = sv;
    __syncthreads();
    if (t < 16) {
        int ws2 = wsum[t];
        #pragma unroll
        for (int o = 1; o < 16; o <<= 1) {
            int u = __shfl_up(ws2, o, 16);
            if (t >= o) ws2 += u;
        }
        wsum[t] = ws2;
    }
    __syncthreads();
    int excl = sv - v + (w ? wsum[w - 1] : 0);
    if (t < nb) { bucket_start[t] = excl; bucket_cursor[t] = excl; }
    if (t == nb - 1) bucket_start[nb] = excl + v;
}

__global__ void k_scat(const int* __restrict__ ei, const int* __restrict__ blockhist,
                       int* __restrict__ bucket_cursor, int* __restrict__ pairbuf,
                       int E, int N, int nb) {
    __shared__ int h[1024];
    __shared__ int basearr[1024];
    for (int i = threadIdx.x; i < nb; i += 256) {
        int c = blockhist[(size_t)blockIdx.x * 1024 + i];
        basearr[i] = c ? atomicAdd(&bucket_cursor[i], c) : 0;
        h[i] = 0;
    }
    __syncthreads();
    int ET = E + N;
    int base = blockIdx.x * 8192;
    int end = base + 8192 < ET ? base + 8192 : ET;
    for (int e = base + threadIdx.x; e < end; e += 256) {
        int s, d;
        if (e < E) { s = ei[e]; d = ei[E + e]; } else { s = d = e - E; }
        int b = d >> 7;
        int pos = basearr[b] + atomicAdd(&h[b], 1);
        pairbuf[pos] = (s << 7) | (d & 127);
    }
}

__global__ void k_build(const int* __restrict__ pairbuf, const int* __restrict__ bucket_start,
                        int* __restrict__ rowp, int* __restrict__ col, int N, int nb) {
    int b = blockIdx.x;
    __shared__ int deg[128];
    __shared__ int inc[128];
    __shared__ int rbase[128];
    __shared__ int cur[128];
    int s0 = bucket_start[b], s1 = bucket_start[b + 1];
    if (threadIdx.x < 128) deg[threadIdx.x] = 0;
    __syncthreads();
    for (int i = s0 + threadIdx.x; i < s1; i += 256)
        atomicAdd(&deg[pairbuf[i] & 127], 1);
    __syncthreads();
    if (threadIdx.x < 128) {
        int lane = threadIdx.x & 63;
        int sv = deg[threadIdx.x];
        #pragma unroll
        for (int o = 1; o < 64; o <<= 1) {
            int u = __shfl_up(sv, o, 64);
            if (lane >= o) sv += u;
        }
        inc[threadIdx.x] = sv;
    }
    __syncthreads();
    if (threadIdx.x < 128) {
        int excl = inc[threadIdx.x] - deg[threadIdx.x] + ((threadIdx.x >= 64) ? inc[63] : 0);
        rbase[threadIdx.x] = s0 + excl;
        cur[threadIdx.x] = 0;
        int node = (b << 7) + threadIdx.x;
        if (node < N) rowp[node] = s0 + excl;
    }
    __syncthreads();
    for (int i = s0 + threadIdx.x; i < s1; i += 256) {
        int p = pairbuf[i];
        int off = p & 127;
        int pos = rbase[off] + atomicAdd(&cur[off], 1);
        col[pos] = p >> 7;
    }
    if (b == 0 && threadIdx.x == 0) rowp[N] = bucket_start[nb];
}

// ---------------- layer 1: branch-free softmax (no max shift; |logit| small) ----------------
__global__ void k_layer1(const float* __restrict__ x, const int* __restrict__ rowp,
                         const int* __restrict__ col, const float* __restrict__ dots,
                         float* __restrict__ S, int N) {
    int gid = blockIdx.x * blockDim.x + threadIdx.x;
    int n = gid >> 4;               // 16 lanes per node
    int lane = threadIdx.x & 15;
    if (n >= N) return;
    int s = rowp[n];
    int deg = rowp[n + 1] - s;
    float xd = x[n];
    float ds0 = dots[0], ds1 = dots[1], ds2 = dots[2], ds3 = dots[3];
    float t0 = xd * dots[4], t1 = xd * dots[5], t2 = xd * dots[6], t3 = xd * dots[7];
    float p0 = 0.f, p1 = 0.f, p2 = 0.f, p3 = 0.f;
    float q0 = 0.f, q1 = 0.f, q2 = 0.f, q3 = 0.f;
    for (int i = lane; i < deg; i += 16) {
        float xs = x[col[s + i]];
        float e0 = LRELU(fmaf(xs, ds0, t0)); float w0 = __expf(e0); p0 += w0; q0 = fmaf(w0, xs, q0);
        float e1 = LRELU(fmaf(xs, ds1, t1)); float w1 = __expf(e1); p1 += w1; q1 = fmaf(w1, xs, q1);
        float e2 = LRELU(fmaf(xs, ds2, t2)); float w2 = __expf(e2); p2 += w2; q2 = fmaf(w2, xs, q2);
        float e3 = LRELU(fmaf(xs, ds3, t3)); float w3 = __expf(e3); p3 += w3; q3 = fmaf(w3, xs, q3);
    }
    #pragma unroll
    for (int o = 8; o; o >>= 1) {
        p0 += __shfl_xor(p0, o, 16); p1 += __shfl_xor(p1, o, 16);
        p2 += __shfl_xor(p2, o, 16); p3 += __shfl_xor(p3, o, 16);
        q0 += __shfl_xor(q0, o, 16); q1 += __shfl_xor(q1, o, 16);
        q2 += __shfl_xor(q2, o, 16); q3 += __shfl_xor(q3, o, 16);
    }
    if (lane == 0) {
        float4 r;
        r.x = q0 / (p0 + 1e-16f);
        r.y = q1 / (p1 + 1e-16f);
        r.z = q2 / (p2 + 1e-16f);
        r.w = q3 / (p3 + 1e-16f);
        *(float4*)(S + n * 4) = r;
    }
}

// ---------------- layer 2 node transform: h2 stored as fp8 e4m3 rows (32 B) ----------------
__global__ void k_h2(const float* __restrict__ S, const float* __restrict__ W1,
                     const float* __restrict__ b1, const float* __restrict__ W2,
                     const float* __restrict__ a2s, const float* __restrict__ a2d,
                     unsigned int* __restrict__ h2f8, float* __restrict__ es2,
                     float* __restrict__ ed2, int N) {
    __shared__ float sW2[4096];
    __shared__ float sW1[128];
    __shared__ float sb1[128];
    for (int i = threadIdx.x; i < 4096; i += blockDim.x) sW2[i] = W2[i];
    if (threadIdx.x < 128) {
        sW1[threadIdx.x] = W1[threadIdx.x];
        sb1[threadIdx.x] = b1[threadIdx.x];
    }
    __syncthreads();
    int n = blockIdx.x * blockDim.x + threadIdx.x;
    if (n >= N) return;
    float sv0 = S[n * 4 + 0], sv1 = S[n * 4 + 1], sv2 = S[n * 4 + 2], sv3 = S[n * 4 + 3];
    float acc[32];
    #pragma unroll
    for (int c = 0; c < 32; ++c) acc[c] = 0.f;
    #pragma unroll
    for (int h = 0; h < 4; ++h) {
        float sh = (h == 0) ? sv0 : (h == 1) ? sv1 : (h == 2) ? sv2 : sv3;
        for (int cc = 0; cc < 32; ++cc) {
            int hc = h * 32 + cc;
            float x1 = fmaf(sh, sW1[hc], sb1[hc]);
            x1 = x1 > 0.f ? x1 : 0.f;
            const float* w2row = &sW2[hc * 32];
            #pragma unroll
            for (int c = 0; c < 32; ++c) acc[c] = fmaf(x1, w2row[c], acc[c]);
        }
    }
    float es = 0.f, edv = 0.f;
    #pragma unroll
    for (int c = 0; c < 32; ++c) {
        es = fmaf(acc[c], a2s[c], es);
        edv = fmaf(acc[c], a2d[c], edv);
    }
    alignas(16) unsigned int hw[8];
    #pragma unroll
    for (int q = 0; q < 8; ++q) {
        int w = __builtin_amdgcn_cvt_pk_fp8_f32(acc[4 * q + 0], acc[4 * q + 1], 0, false);
        w = __builtin_amdgcn_cvt_pk_fp8_f32(acc[4 * q + 2], acc[4 * q + 3], w, true);
        hw[q] = (unsigned int)w;
    }
    uint4* dst = (uint4*)(h2f8 + (size_t)n * 8);
    dst[0] = ((const uint4*)hw)[0];
    dst[1] = ((const uint4*)hw)[1];
    es2[n] = es;
    ed2[n] = edv;
}

// ---------------- layer 2 aggregation: fp8 h2 gathers, bf16 x2 output ----------------
__global__ void k_agg(const unsigned int* __restrict__ h2f8, const float* __restrict__ es2,
                      const float* __restrict__ ed2, const int* __restrict__ rowp,
                      const int* __restrict__ col, const float* __restrict__ b2,
                      unsigned short* __restrict__ x2buf, int N) {
    int gid = blockIdx.x * blockDim.x + threadIdx.x;
    int n = gid >> 6;               // 64 lanes per node
    int lane = threadIdx.x & 63;
    if (n >= N) return;
    int s = rowp[n];
    int deg = rowp[n + 1] - s;
    float ed = ed2[n];
    int slot = lane >> 2;           // 16 edge slots
    int cg = lane & 3;              // 4 channel-groups of 8 channels
    float sump = 0.f;
    float a0 = 0.f, a1 = 0.f, a2 = 0.f, a3 = 0.f, a4 = 0.f, a5 = 0.f, a6 = 0.f, a7 = 0.f;
    for (int j = slot; j < deg; j += 16) {
        int sidx = col[s + j];
        float e = LRELU(es2[sidx] + ed);
        float p = __expf(e);
        sump += p;
        uint2 hv = *(const uint2*)(h2f8 + (size_t)sidx * 8 + cg * 2);
        f32x2 c01 = __builtin_amdgcn_cvt_pk_f32_fp8((int)hv.x, false);
        f32x2 c23 = __builtin_amdgcn_cvt_pk_f32_fp8((int)hv.x, true);
        f32x2 c45 = __builtin_amdgcn_cvt_pk_f32_fp8((int)hv.y, false);
        f32x2 c67 = __builtin_amdgcn_cvt_pk_f32_fp8((int)hv.y, true);
        a0 = fmaf(p, c01.x, a0); a1 = fmaf(p, c01.y, a1);
        a2 = fmaf(p, c23.x, a2); a3 = fmaf(p, c23.y, a3);
        a4 = fmaf(p, c45.x, a4); a5 = fmaf(p, c45.y, a5);
        a6 = fmaf(p, c67.x, a6); a7 = fmaf(p, c67.y, a7);
    }
    #pragma unroll
    for (int o = 4; o <= 32; o <<= 1) {
        sump += __shfl_xor(sump, o, 64);
        a0 += __shfl_xor(a0, o, 64); a1 += __shfl_xor(a1, o, 64);
        a2 += __shfl_xor(a2, o, 64); a3 += __shfl_xor(a3, o, 64);
        a4 += __shfl_xor(a4, o, 64); a5 += __shfl_xor(a5, o, 64);
        a6 += __shfl_xor(a6, o, 64); a7 += __shfl_xor(a7, o, 64);
    }
    if (slot == 0) {                // lanes 0..3, each owns channels 8cg..8cg+7
        float inv = 1.0f / (sump + 1e-16f);
        const float* bb = b2 + cg * 8;
        float v[8] = {a0, a1, a2, a3, a4, a5, a6, a7};
        unsigned int w[4];
        #pragma unroll
        for (int q = 0; q < 4; ++q) {
            float t0 = fmaf(v[2 * q], inv, bb[2 * q]);
            t0 = t0 > 0.f ? t0 : 0.f;
            float t1 = fmaf(v[2 * q + 1], inv, bb[2 * q + 1]);
            t1 = t1 > 0.f ? t1 : 0.f;
            w[q] = (unsigned int)f2bf(t0) | ((unsigned int)f2bf(t1) << 16);
        }
        uint4* dst = (uint4*)(x2buf + (size_t)n * 32 + cg * 8);
        *dst = make_uint4(w[0], w[1], w[2], w[3]);
    }
}

// ---------------- pooling stage 1: G*PPARTS blocks, no atomics ----------------
__global__ void k_psum(const unsigned short* __restrict__ x2buf, const int* __restrict__ batch,
                       float* __restrict__ partial, int N) {
    int g = blockIdx.x / PPARTS;
    int part = blockIdx.x % PPARTS;
    __shared__ int sr[2];
    if (threadIdx.x == 0) {
        int lo = 0, hi = N;
        while (lo < hi) { int mid = (lo + hi) >> 1; if (batch[mid] < g) lo = mid + 1; else hi = mid; }
        sr[0] = lo;
        int l2 = lo, h2v = N;
        while (l2 < h2v) { int mid = (l2 + h2v) >> 1; if (batch[mid] < g + 1) l2 = mid + 1; else h2v = mid; }
        sr[1] = l2;
    }
    __syncthreads();
    int lo = sr[0], hi = sr[1];
    int cs = (hi - lo + PPARTS - 1) / PPARTS;
    int start = lo + part * cs;
    int end = start + cs < hi ? start + cs : hi;
    int ch = threadIdx.x & 31;
    int slot = threadIdx.x >> 5;    // 8 node slots
    float acc = 0.f;
    for (int n = start + slot; n < end; n += 8)
        acc += bf2f(x2buf[(size_t)n * 32 + ch]);
    __shared__ float red[256];
    red[threadIdx.x] = acc;
    __syncthreads();
    #pragma unroll
    for (int o = 128; o >= 32; o >>= 1) {
        if (threadIdx.x < o) red[threadIdx.x] += red[threadIdx.x + o];
        __syncthreads();
    }
    if (threadIdx.x < 32)
        partial[(size_t)(g * PPARTS + part) * 32 + threadIdx.x] = red[threadIdx.x];
}

// ---------------- pooling stage 2 + head: one block per graph ----------------
__global__ void k_head(const float* __restrict__ partial, const int* __restrict__ batch,
                       const float* __restrict__ lin_w, const float* __restrict__ lin_b,
                       float* __restrict__ out, int N) {
    int g = blockIdx.x;
    int t = threadIdx.x;            // 64 threads
    int ch = t & 31;
    int half = t >> 5;
    float acc = 0.f;
    for (int p = half * (PPARTS / 2); p < (half + 1) * (PPARTS / 2); ++p)
        acc += partial[(size_t)(g * PPARTS + p) * 32 + ch];
    acc += __shfl_xor(acc, 32, 64);
    int lo = 0, hi = N;
    while (lo < hi) { int mid = (lo + hi) >> 1; if (batch[mid] < g) lo = mid + 1; else hi = mid; }
    int l2 = lo, h2v = N;
    while (l2 < h2v) { int mid = (l2 + h2v) >> 1; if (batch[mid] < g + 1) l2 = mid + 1; else h2v = mid; }
    float c = fmaxf((float)(h2v - lo), 1.0f);
    float v = acc / c * lin_w[ch];
    #pragma unroll
    for (int o = 16; o; o >>= 1) v += __shfl_xor(v, o, 32);
    if (t == 0) out[g] = 1.0f / (1.0f + __expf(-(v + lin_b[0])));
}

extern "C" void kernel_launch(void* const* d_in, const int* in_sizes, int n_in,
                              void* d_out, int out_size, void* d_ws, size_t ws_size,
                              hipStream_t stream) {
    const float* x     = (const float*)d_in[0];
    const int*   ei    = (const int*)d_in[1];
    const int*   batch = (const int*)d_in[2];
    const float* W1    = (const float*)d_in[4];
    const float* a1s   = (const float*)d_in[5];
    const float* a1d   = (const float*)d_in[6];
    const float* b1    = (const float*)d_in[7];
    const float* W2    = (const float*)d_in[8];
    const float* a2s   = (const float*)d_in[9];
    const float* a2d   = (const float*)d_in[10];
    const float* b2    = (const float*)d_in[11];
    const float* lin_w = (const float*)d_in[12];
    const float* lin_b = (const float*)d_in[13];
    float* out = (float*)d_out;

    int N = in_sizes[0];
    int E = in_sizes[1] / 2;
    int ET = E + N;
    int G = out_size;
    int nb = (N + 127) >> 7;        // dst-buckets of 128 nodes
    int nblk = (ET + 8191) / 8192;

    char* ws = (char*)d_ws;
    size_t off = 0;
    auto alloc = [&](size_t bytes) -> char* {
        char* p = ws + off;
        off = (off + bytes + 255) & ~(size_t)255;
        return p;
    };
    int*   bucket_cnt    = (int*)alloc(1024 * 4);
    int*   bucket_start  = (int*)alloc(1025 * 4);
    int*   bucket_cursor = (int*)alloc(1024 * 4);
    int*   blockhist     = (int*)alloc((size_t)nblk * 1024 * 4);
    int*   pairbuf = (int*)alloc((size_t)ET * 4);
    int*   rowp    = (int*)alloc((size_t)(N + 1) * 4);
    int*   col     = (int*)alloc((size_t)ET * 4);
    float* S       = (float*)alloc((size_t)N * 16);
    unsigned int* h2f8 = (unsigned int*)alloc((size_t)N * 32);
    float* es2     = (float*)alloc((size_t)N * 4);
    float* ed2     = (float*)alloc((size_t)N * 4);
    float* dots    = (float*)alloc(32);
    unsigned short* x2buf = (unsigned short*)alloc((size_t)N * 64);
    float* partial = (float*)alloc((size_t)G * PPARTS * 32 * 4);

    hipMemsetAsync(bucket_cnt, 0, (size_t)nb * 4, stream);

    k_cnt<<<nblk, 256, 0, stream>>>(ei, bucket_cnt, blockhist, E, N, nb);
    k_scanB<<<1, 1024, 0, stream>>>(bucket_cnt, bucket_start, bucket_cursor, nb, W1, a1s, a1d, dots);
    k_scat<<<nblk, 256, 0, stream>>>(ei, blockhist, bucket_cursor, pairbuf, E, N, nb);
    k_build<<<nb, 256, 0, stream>>>(pairbuf, bucket_start, rowp, col, N, nb);
    k_layer1<<<(N + 15) / 16, 256, 0, stream>>>(x, rowp, col, dots, S, N);
    k_h2<<<(N + 255) / 256, 256, 0, stream>>>(S, W1, b1, W2, a2s, a2d, h2f8, es2, ed2, N);
    k_agg<<<((size_t)N * 64 + 255) / 256, 256, 0, stream>>>(h2f8, es2, ed2, rowp, col, b2, x2buf, N);
    k_psum<<<G * PPARTS, 256, 0, stream>>>(x2buf, batch, partial, N);
    k_head<<<G, 64, 0, stream>>>(partial, batch, lin_w, lin_b, out, N);
}

// Round 9
// 154.102 us; speedup vs baseline: 9.2768x; 1.0852x over previous
//
#include <hip/hip_runtime.h>
#include <hip/hip_bf16.h>

#define LRELU(v) ((v) > 0.0f ? (v) : 0.2f * (v))
#define PPARTS 32

typedef float f32x2 __attribute__((ext_vector_type(2)));

__device__ __forceinline__ unsigned short f2bf(float f) {
    unsigned int u = __float_as_uint(f);
    unsigned int r = (u >> 16) & 1;
    u += 0x7fff + r;                 // round-to-nearest-even
    return (unsigned short)(u >> 16);
}
__device__ __forceinline__ float bf2f(unsigned short s) {
    return __uint_as_float(((unsigned int)s) << 16);
}

// ================= CSR build via dst-bucket sort (128 dst-nodes per bucket) =================
__global__ void k_cnt(const int* __restrict__ ei, int* __restrict__ bucket_cnt,
                      int* __restrict__ blockhist, int E, int N, int nb) {
    __shared__ int h[1024];
    for (int i = threadIdx.x; i < nb; i += 256) h[i] = 0;
    __syncthreads();
    int ET = E + N;
    int base = blockIdx.x * 8192;
    int end = base + 8192 < ET ? base + 8192 : ET;
    for (int e = base + threadIdx.x; e < end; e += 256) {
        int d = (e < E) ? ei[E + e] : (e - E);
        atomicAdd(&h[d >> 7], 1);
    }
    __syncthreads();
    for (int i = threadIdx.x; i < nb; i += 256) {
        int c = h[i];
        if (c) atomicAdd(&bucket_cnt[i], c);
        blockhist[(size_t)blockIdx.x * 1024 + i] = c;
    }
}

__global__ void k_scanB(const int* __restrict__ bucket_cnt, int* __restrict__ bucket_start,
                        int* __restrict__ bucket_cursor, int nb,
                        const float* __restrict__ W1, const float* __restrict__ a1s,
                        const float* __restrict__ a1d, float* __restrict__ dots) {
    int t = threadIdx.x;            // 1024 threads
    if (t < 128) {                  // fused k_pre
        float w = W1[t];
        float ps = w * a1s[t];
        float pd = w * a1d[t];
        #pragma unroll
        for (int o = 16; o; o >>= 1) {
            ps += __shfl_xor(ps, o, 32);
            pd += __shfl_xor(pd, o, 32);
        }
        if ((t & 31) == 0) {
            dots[t >> 5] = ps;
            dots[4 + (t >> 5)] = pd;
        }
    }
    __shared__ int wsum[16];
    int v = (t < nb) ? bucket_cnt[t] : 0;
    int lane = t & 63, w = t >> 6;
    int sv = v;
    #pragma unroll
    for (int o = 1; o < 64; o <<= 1) {
        int u = __shfl_up(sv, o, 64);
        if (lane >= o) sv += u;
    }
    if (lane == 63) wsum[w] = sv;
    __syncthreads();
    if (t < 16) {
        int ws2 = wsum[t];
        #pragma unroll
        for (int o = 1; o < 16; o <<= 1) {
            int u = __shfl_up(ws2, o, 16);
            if (t >= o) ws2 += u;
        }
        wsum[t] = ws2;
    }
    __syncthreads();
    int excl = sv - v + (w ? wsum[w - 1] : 0);
    if (t < nb) { bucket_start[t] = excl; bucket_cursor[t] = excl; }
    if (t == nb - 1) bucket_start[nb] = excl + v;
}

__global__ void k_scat(const int* __restrict__ ei, const int* __restrict__ blockhist,
                       int* __restrict__ bucket_cursor, int* __restrict__ pairbuf,
                       int E, int N, int nb) {
    __shared__ int h[1024];
    __shared__ int basearr[1024];
    for (int i = threadIdx.x; i < nb; i += 256) {
        int c = blockhist[(size_t)blockIdx.x * 1024 + i];
        basearr[i] = c ? atomicAdd(&bucket_cursor[i], c) : 0;
        h[i] = 0;
    }
    __syncthreads();
    int ET = E + N;
    int base = blockIdx.x * 8192;
    int end = base + 8192 < ET ? base + 8192 : ET;
    for (int e = base + threadIdx.x; e < end; e += 256) {
        int s, d;
        if (e < E) { s = ei[e]; d = ei[E + e]; } else { s = d = e - E; }
        int b = d >> 7;
        int pos = basearr[b] + atomicAdd(&h[b], 1);
        pairbuf[pos] = (s << 7) | (d & 127);
    }
}

__global__ void k_build(const int* __restrict__ pairbuf, const int* __restrict__ bucket_start,
                        int* __restrict__ rowp, int* __restrict__ col, int N, int nb) {
    int b = blockIdx.x;
    __shared__ int deg[128];
    __shared__ int inc[128];
    __shared__ int rbase[128];
    __shared__ int cur[128];
    int s0 = bucket_start[b], s1 = bucket_start[b + 1];
    if (threadIdx.x < 128) deg[threadIdx.x] = 0;
    __syncthreads();
    for (int i = s0 + threadIdx.x; i < s1; i += 256)
        atomicAdd(&deg[pairbuf[i] & 127], 1);
    __syncthreads();
    if (threadIdx.x < 128) {
        int lane = threadIdx.x & 63;
        int sv = deg[threadIdx.x];
        #pragma unroll
        for (int o = 1; o < 64; o <<= 1) {
            int u = __shfl_up(sv, o, 64);
            if (lane >= o) sv += u;
        }
        inc[threadIdx.x] = sv;
    }
    __syncthreads();
    if (threadIdx.x < 128) {
        int excl = inc[threadIdx.x] - deg[threadIdx.x] + ((threadIdx.x >= 64) ? inc[63] : 0);
        rbase[threadIdx.x] = s0 + excl;
        cur[threadIdx.x] = 0;
        int node = (b << 7) + threadIdx.x;
        if (node < N) rowp[node] = s0 + excl;
    }
    __syncthreads();
    for (int i = s0 + threadIdx.x; i < s1; i += 256) {
        int p = pairbuf[i];
        int off = p & 127;
        int pos = rbase[off] + atomicAdd(&cur[off], 1);
        col[pos] = p >> 7;
    }
    if (b == 0 && threadIdx.x == 0) rowp[N] = bucket_start[nb];
}

// ---------------- layer 1: branch-free softmax (no max shift; |logit| small) ----------------
__global__ void k_layer1(const float* __restrict__ x, const int* __restrict__ rowp,
                         const int* __restrict__ col, const float* __restrict__ dots,
                         float* __restrict__ S, int N) {
    int gid = blockIdx.x * blockDim.x + threadIdx.x;
    int n = gid >> 4;               // 16 lanes per node
    int lane = threadIdx.x & 15;
    if (n >= N) return;
    int s = rowp[n];
    int deg = rowp[n + 1] - s;
    float xd = x[n];
    float ds0 = dots[0], ds1 = dots[1], ds2 = dots[2], ds3 = dots[3];
    float t0 = xd * dots[4], t1 = xd * dots[5], t2 = xd * dots[6], t3 = xd * dots[7];
    float p0 = 0.f, p1 = 0.f, p2 = 0.f, p3 = 0.f;
    float q0 = 0.f, q1 = 0.f, q2 = 0.f, q3 = 0.f;
    for (int i = lane; i < deg; i += 16) {
        float xs = x[col[s + i]];
        float e0 = LRELU(fmaf(xs, ds0, t0)); float w0 = __expf(e0); p0 += w0; q0 = fmaf(w0, xs, q0);
        float e1 = LRELU(fmaf(xs, ds1, t1)); float w1 = __expf(e1); p1 += w1; q1 = fmaf(w1, xs, q1);
        float e2 = LRELU(fmaf(xs, ds2, t2)); float w2 = __expf(e2); p2 += w2; q2 = fmaf(w2, xs, q2);
        float e3 = LRELU(fmaf(xs, ds3, t3)); float w3 = __expf(e3); p3 += w3; q3 = fmaf(w3, xs, q3);
    }
    #pragma unroll
    for (int o = 8; o; o >>= 1) {
        p0 += __shfl_xor(p0, o, 16); p1 += __shfl_xor(p1, o, 16);
        p2 += __shfl_xor(p2, o, 16); p3 += __shfl_xor(p3, o, 16);
        q0 += __shfl_xor(q0, o, 16); q1 += __shfl_xor(q1, o, 16);
        q2 += __shfl_xor(q2, o, 16); q3 += __shfl_xor(q3, o, 16);
    }
    if (lane == 0) {
        float4 r;
        r.x = q0 / (p0 + 1e-16f);
        r.y = q1 / (p1 + 1e-16f);
        r.z = q2 / (p2 + 1e-16f);
        r.w = q3 / (p3 + 1e-16f);
        *(float4*)(S + n * 4) = r;
    }
}

// ---------------- layer 2 node transform: h2 stored as fp8 e4m3 rows (32 B) ----------------
__global__ void k_h2(const float* __restrict__ S, const float* __restrict__ W1,
                     const float* __restrict__ b1, const float* __restrict__ W2,
                     const float* __restrict__ a2s, const float* __restrict__ a2d,
                     unsigned int* __restrict__ h2f8, float* __restrict__ es2,
                     float* __restrict__ ed2, int N) {
    __shared__ float sW2[4096];
    __shared__ float sW1[128];
    __shared__ float sb1[128];
    for (int i = threadIdx.x; i < 4096; i += blockDim.x) sW2[i] = W2[i];
    if (threadIdx.x < 128) {
        sW1[threadIdx.x] = W1[threadIdx.x];
        sb1[threadIdx.x] = b1[threadIdx.x];
    }
    __syncthreads();
    int n = blockIdx.x * blockDim.x + threadIdx.x;
    if (n >= N) return;
    float sv0 = S[n * 4 + 0], sv1 = S[n * 4 + 1], sv2 = S[n * 4 + 2], sv3 = S[n * 4 + 3];
    float acc[32];
    #pragma unroll
    for (int c = 0; c < 32; ++c) acc[c] = 0.f;
    #pragma unroll
    for (int h = 0; h < 4; ++h) {
        float sh = (h == 0) ? sv0 : (h == 1) ? sv1 : (h == 2) ? sv2 : sv3;
        for (int cc = 0; cc < 32; ++cc) {
            int hc = h * 32 + cc;
            float x1 = fmaf(sh, sW1[hc], sb1[hc]);
            x1 = x1 > 0.f ? x1 : 0.f;
            const float* w2row = &sW2[hc * 32];
            #pragma unroll
            for (int c = 0; c < 32; ++c) acc[c] = fmaf(x1, w2row[c], acc[c]);
        }
    }
    float es = 0.f, edv = 0.f;
    #pragma unroll
    for (int c = 0; c < 32; ++c) {
        es = fmaf(acc[c], a2s[c], es);
        edv = fmaf(acc[c], a2d[c], edv);
    }
    alignas(16) unsigned int hw[8];
    #pragma unroll
    for (int q = 0; q < 8; ++q) {
        int w = __builtin_amdgcn_cvt_pk_fp8_f32(acc[4 * q + 0], acc[4 * q + 1], 0, false);
        w = __builtin_amdgcn_cvt_pk_fp8_f32(acc[4 * q + 2], acc[4 * q + 3], w, true);
        hw[q] = (unsigned int)w;
    }
    uint4* dst = (uint4*)(h2f8 + (size_t)n * 8);
    dst[0] = ((const uint4*)hw)[0];
    dst[1] = ((const uint4*)hw)[1];
    es2[n] = es;
    ed2[n] = edv;
}

// ---------------- layer 2 aggregation: 16 lanes/node = 4 edge-slots x 4 channel-groups ----------------
__global__ void k_agg(const unsigned int* __restrict__ h2f8, const float* __restrict__ es2,
                      const float* __restrict__ ed2, const int* __restrict__ rowp,
                      const int* __restrict__ col, const float* __restrict__ b2,
                      unsigned short* __restrict__ x2buf, int N) {
    int gid = blockIdx.x * blockDim.x + threadIdx.x;
    int n = gid >> 4;               // 16 lanes per node (4 nodes per wave)
    int lane = threadIdx.x & 15;
    if (n >= N) return;
    int s = rowp[n];
    int deg = rowp[n + 1] - s;
    float ed = ed2[n];
    int slot = lane >> 2;           // 4 edge slots
    int cg = lane & 3;              // 4 channel-groups of 8 channels
    float sump = 0.f;
    float a0 = 0.f, a1 = 0.f, a2 = 0.f, a3 = 0.f, a4 = 0.f, a5 = 0.f, a6 = 0.f, a7 = 0.f;
    for (int j = slot; j < deg; j += 4) {
        int sidx = col[s + j];
        float e = LRELU(es2[sidx] + ed);
        float p = __expf(e);
        sump += p;
        uint2 hv = *(const uint2*)(h2f8 + (size_t)sidx * 8 + cg * 2);
        f32x2 c01 = __builtin_amdgcn_cvt_pk_f32_fp8((int)hv.x, false);
        f32x2 c23 = __builtin_amdgcn_cvt_pk_f32_fp8((int)hv.x, true);
        f32x2 c45 = __builtin_amdgcn_cvt_pk_f32_fp8((int)hv.y, false);
        f32x2 c67 = __builtin_amdgcn_cvt_pk_f32_fp8((int)hv.y, true);
        a0 = fmaf(p, c01.x, a0); a1 = fmaf(p, c01.y, a1);
        a2 = fmaf(p, c23.x, a2); a3 = fmaf(p, c23.y, a3);
        a4 = fmaf(p, c45.x, a4); a5 = fmaf(p, c45.y, a5);
        a6 = fmaf(p, c67.x, a6); a7 = fmaf(p, c67.y, a7);
    }
    // reduce across the 4 edge-slots (lane bits 2,3)
    #pragma unroll
    for (int o = 4; o <= 8; o <<= 1) {
        sump += __shfl_xor(sump, o, 16);
        a0 += __shfl_xor(a0, o, 16); a1 += __shfl_xor(a1, o, 16);
        a2 += __shfl_xor(a2, o, 16); a3 += __shfl_xor(a3, o, 16);
        a4 += __shfl_xor(a4, o, 16); a5 += __shfl_xor(a5, o, 16);
        a6 += __shfl_xor(a6, o, 16); a7 += __shfl_xor(a7, o, 16);
    }
    if (slot == 0) {                // lanes 0..3 of each 16-group, each owns channels 8cg..8cg+7
        float inv = 1.0f / (sump + 1e-16f);
        const float* bb = b2 + cg * 8;
        float v[8] = {a0, a1, a2, a3, a4, a5, a6, a7};
        unsigned int w[4];
        #pragma unroll
        for (int q = 0; q < 4; ++q) {
            float t0 = fmaf(v[2 * q], inv, bb[2 * q]);
            t0 = t0 > 0.f ? t0 : 0.f;
            float t1 = fmaf(v[2 * q + 1], inv, bb[2 * q + 1]);
            t1 = t1 > 0.f ? t1 : 0.f;
            w[q] = (unsigned int)f2bf(t0) | ((unsigned int)f2bf(t1) << 16);
        }
        uint4* dst = (uint4*)(x2buf + (size_t)n * 32 + cg * 8);
        *dst = make_uint4(w[0], w[1], w[2], w[3]);
    }
}

// ---------------- pooling stage 1: G*PPARTS blocks, no atomics ----------------
__global__ void k_psum(const unsigned short* __restrict__ x2buf, const int* __restrict__ batch,
                       float* __restrict__ partial, int N) {
    int g = blockIdx.x / PPARTS;
    int part = blockIdx.x % PPARTS;
    __shared__ int sr[2];
    if (threadIdx.x == 0) {
        int lo = 0, hi = N;
        while (lo < hi) { int mid = (lo + hi) >> 1; if (batch[mid] < g) lo = mid + 1; else hi = mid; }
        sr[0] = lo;
        int l2 = lo, h2v = N;
        while (l2 < h2v) { int mid = (l2 + h2v) >> 1; if (batch[mid] < g + 1) l2 = mid + 1; else h2v = mid; }
        sr[1] = l2;
    }
    __syncthreads();
    int lo = sr[0], hi = sr[1];
    int cs = (hi - lo + PPARTS - 1) / PPARTS;
    int start = lo + part * cs;
    int end = start + cs < hi ? start + cs : hi;
    int ch = threadIdx.x & 31;
    int slot = threadIdx.x >> 5;    // 8 node slots
    float acc = 0.f;
    for (int n = start + slot; n < end; n += 8)
        acc += bf2f(x2buf[(size_t)n * 32 + ch]);
    __shared__ float red[256];
    red[threadIdx.x] = acc;
    __syncthreads();
    #pragma unroll
    for (int o = 128; o >= 32; o >>= 1) {
        if (threadIdx.x < o) red[threadIdx.x] += red[threadIdx.x + o];
        __syncthreads();
    }
    if (threadIdx.x < 32)
        partial[(size_t)(g * PPARTS + part) * 32 + threadIdx.x] = red[threadIdx.x];
}

// ---------------- pooling stage 2 + head: one block per graph ----------------
__global__ void k_head(const float* __restrict__ partial, const int* __restrict__ batch,
                       const float* __restrict__ lin_w, const float* __restrict__ lin_b,
                       float* __restrict__ out, int N) {
    int g = blockIdx.x;
    int t = threadIdx.x;            // 64 threads
    int ch = t & 31;
    int half = t >> 5;
    float acc = 0.f;
    for (int p = half * (PPARTS / 2); p < (half + 1) * (PPARTS / 2); ++p)
        acc += partial[(size_t)(g * PPARTS + p) * 32 + ch];
    acc += __shfl_xor(acc, 32, 64);
    int lo = 0, hi = N;
    while (lo < hi) { int mid = (lo + hi) >> 1; if (batch[mid] < g) lo = mid + 1; else hi = mid; }
    int l2 = lo, h2v = N;
    while (l2 < h2v) { int mid = (l2 + h2v) >> 1; if (batch[mid] < g + 1) l2 = mid + 1; else h2v = mid; }
    float c = fmaxf((float)(h2v - lo), 1.0f);
    float v = acc / c * lin_w[ch];
    #pragma unroll
    for (int o = 16; o; o >>= 1) v += __shfl_xor(v, o, 32);
    if (t == 0) out[g] = 1.0f / (1.0f + __expf(-(v + lin_b[0])));
}

extern "C" void kernel_launch(void* const* d_in, const int* in_sizes, int n_in,
                              void* d_out, int out_size, void* d_ws, size_t ws_size,
                              hipStream_t stream) {
    const float* x     = (const float*)d_in[0];
    const int*   ei    = (const int*)d_in[1];
    const int*   batch = (const int*)d_in[2];
    const float* W1    = (const float*)d_in[4];
    const float* a1s   = (const float*)d_in[5];
    const float* a1d   = (const float*)d_in[6];
    const float* b1    = (const float*)d_in[7];
    const float* W2    = (const float*)d_in[8];
    const float* a2s   = (const float*)d_in[9];
    const float* a2d   = (const float*)d_in[10];
    const float* b2    = (const float*)d_in[11];
    const float* lin_w = (const float*)d_in[12];
    const float* lin_b = (const float*)d_in[13];
    float* out = (float*)d_out;

    int N = in_sizes[0];
    int E = in_sizes[1] / 2;
    int ET = E + N;
    int G = out_size;
    int nb = (N + 127) >> 7;        // dst-buckets of 128 nodes
    int nblk = (ET + 8191) / 8192;

    char* ws = (char*)d_ws;
    size_t off = 0;
    auto alloc = [&](size_t bytes) -> char* {
        char* p = ws + off;
        off = (off + bytes + 255) & ~(size_t)255;
        return p;
    };
    int*   bucket_cnt    = (int*)alloc(1024 * 4);
    int*   bucket_start  = (int*)alloc(1025 * 4);
    int*   bucket_cursor = (int*)alloc(1024 * 4);
    int*   blockhist     = (int*)alloc((size_t)nblk * 1024 * 4);
    int*   pairbuf = (int*)alloc((size_t)ET * 4);
    int*   rowp    = (int*)alloc((size_t)(N + 1) * 4);
    int*   col     = (int*)alloc((size_t)ET * 4);
    float* S       = (float*)alloc((size_t)N * 16);
    unsigned int* h2f8 = (unsigned int*)alloc((size_t)N * 32);
    float* es2     = (float*)alloc((size_t)N * 4);
    float* ed2     = (float*)alloc((size_t)N * 4);
    float* dots    = (float*)alloc(32);
    unsigned short* x2buf = (unsigned short*)alloc((size_t)N * 64);
    float* partial = (float*)alloc((size_t)G * PPARTS * 32 * 4);

    hipMemsetAsync(bucket_cnt, 0, (size_t)nb * 4, stream);

    k_cnt<<<nblk, 256, 0, stream>>>(ei, bucket_cnt, blockhist, E, N, nb);
    k_scanB<<<1, 1024, 0, stream>>>(bucket_cnt, bucket_start, bucket_cursor, nb, W1, a1s, a1d, dots);
    k_scat<<<nblk, 256, 0, stream>>>(ei, blockhist, bucket_cursor, pairbuf, E, N, nb);
    k_build<<<nb, 256, 0, stream>>>(pairbuf, bucket_start, rowp, col, N, nb);
    k_layer1<<<(N + 15) / 16, 256, 0, stream>>>(x, rowp, col, dots, S, N);
    k_h2<<<(N + 255) / 256, 256, 0, stream>>>(S, W1, b1, W2, a2s, a2d, h2f8, es2, ed2, N);
    k_agg<<<((size_t)N * 16 + 255) / 256, 256, 0, stream>>>(h2f8, es2, ed2, rowp, col, b2, x2buf, N);
    k_psum<<<G * PPARTS, 256, 0, stream>>>(x2buf, batch, partial, N);
    k_head<<<G, 64, 0, stream>>>(partial, batch, lin_w, lin_b, out, N);
}